// Round 1
// baseline (686.958 us; speedup 1.0000x reference)
//
#include <hip/hip_runtime.h>

#define NN 4096
#define DD 512
#define HH 8
#define FF 64
#define LRELU_ALPHA 0.2f

__device__ __forceinline__ float f4c(const float4& v, int k) {
    return k == 0 ? v.x : (k == 1 ? v.y : (k == 2 ? v.z : v.w));
}
__device__ __forceinline__ void f4s(float4& v, int k, float x) {
    if (k == 0) v.x = x; else if (k == 1) v.y = x; else if (k == 2) v.z = x; else v.w = x;
}

// ---------------- Kernel 1: hp[h][n][f] = sum_d h[n][d] * W[h][d][f] ----------------
// grid (N/64, H), block 256. 64 rows x 64 cols per block, K tiles of 32.
__global__ __launch_bounds__(256) void k_hp(const float* __restrict__ hmat,
                                            const float* __restrict__ W,
                                            float* __restrict__ hp) {
    __shared__ float ht[64 * 36];   // 64 rows x 32 k, stride 36 (16B aligned, bank-friendly)
    __shared__ float wt[32 * 64];   // 32 k x 64 f
    int t = threadIdx.x;
    int hz = blockIdx.y;
    int r0b = blockIdx.x * 64;
    int rg = t >> 4, fg = t & 15;
    int r0 = rg * 4, f0 = fg * 4;
    float acc[4][4] = {};
    for (int kk = 0; kk < DD; kk += 32) {
        #pragma unroll
        for (int ii = 0; ii < 2; ii++) {
            int id = t * 2 + ii;            // 0..511
            int row = id >> 3, k4 = id & 7; // 64 rows x 8 float4
            float4 v = *(const float4*)(hmat + (size_t)(r0b + row) * DD + kk + k4 * 4);
            float* d = ht + row * 36 + k4 * 4;
            d[0] = v.x; d[1] = v.y; d[2] = v.z; d[3] = v.w;
        }
        #pragma unroll
        for (int ii = 0; ii < 2; ii++) {
            int id = t * 2 + ii;             // 0..511
            int k = id >> 4, f4 = id & 15;   // 32 k x 16 float4
            *(float4*)(wt + k * 64 + f4 * 4) =
                *(const float4*)(W + ((size_t)hz * DD + kk + k) * FF + f4 * 4);
        }
        __syncthreads();
        #pragma unroll
        for (int k = 0; k < 32; k++) {
            float a0 = ht[(r0 + 0) * 36 + k];
            float a1 = ht[(r0 + 1) * 36 + k];
            float a2 = ht[(r0 + 2) * 36 + k];
            float a3 = ht[(r0 + 3) * 36 + k];
            float4 b = *(float4*)(wt + k * 64 + f0);
            acc[0][0] += a0 * b.x; acc[0][1] += a0 * b.y; acc[0][2] += a0 * b.z; acc[0][3] += a0 * b.w;
            acc[1][0] += a1 * b.x; acc[1][1] += a1 * b.y; acc[1][2] += a1 * b.z; acc[1][3] += a1 * b.w;
            acc[2][0] += a2 * b.x; acc[2][1] += a2 * b.y; acc[2][2] += a2 * b.z; acc[2][3] += a2 * b.w;
            acc[3][0] += a3 * b.x; acc[3][1] += a3 * b.y; acc[3][2] += a3 * b.z; acc[3][3] += a3 * b.w;
        }
        __syncthreads();
    }
    #pragma unroll
    for (int i = 0; i < 4; i++) {
        float4 o; o.x = acc[i][0]; o.y = acc[i][1]; o.z = acc[i][2]; o.w = acc[i][3];
        *(float4*)(hp + ((size_t)hz * NN + r0b + r0 + i) * FF + f0) = o;
    }
}

// ---------------- Kernel 2: fs/fd = hp . a_src / a_dst (one wave per (h,n)) ----------------
__global__ __launch_bounds__(256) void k_fsfd(const float* __restrict__ hp,
                                              const float* __restrict__ a,
                                              float* __restrict__ fs, float* __restrict__ fd) {
    int t = threadIdx.x;
    int gw = blockIdx.x * 4 + (t >> 6);   // wave id over H*N
    int h = gw >> 12;                     // / 4096
    int n = gw & (NN - 1);
    int f = t & 63;
    float v = hp[((size_t)h * NN + n) * FF + f];
    float vs = v * a[h * 2 * FF + f];
    float vd = v * a[h * 2 * FF + FF + f];
    #pragma unroll
    for (int off = 32; off; off >>= 1) {
        vs += __shfl_xor(vs, off);
        vd += __shfl_xor(vd, off);
    }
    if (f == 0) { fs[(size_t)h * NN + n] = vs; fd[(size_t)h * NN + n] = vd; }
}

// ---------------- Kernel 3: maxfd[h] = max_n fd[h][n] ----------------
__global__ __launch_bounds__(256) void k_maxfd(const float* __restrict__ fd,
                                               float* __restrict__ maxfd) {
    __shared__ float red[256];
    int h = blockIdx.x, t = threadIdx.x;
    float m = -1e30f;
    for (int n = t; n < NN; n += 256) m = fmaxf(m, fd[(size_t)h * NN + n]);
    red[t] = m;
    __syncthreads();
    for (int s = 128; s; s >>= 1) {
        if (t < s) red[t] = fmaxf(red[t], red[t + s]);
        __syncthreads();
    }
    if (t == 0) maxfd[h] = red[0];
}

// ---------------- Kernel 4: hpsum[h][f] = sum_n hp[h][n][f] (degenerate-row fallback) --------
__global__ __launch_bounds__(256) void k_hpsum(const float* __restrict__ hp,
                                               float* __restrict__ hpsum) {
    __shared__ float red[4][64];
    int h = blockIdx.x, t = threadIdx.x;
    int f = t & 63, part = t >> 6;
    float s = 0.f;
    for (int n = part; n < NN; n += 4) s += hp[((size_t)h * NN + n) * FF + f];
    red[part][f] = s;
    __syncthreads();
    if (t < 64) hpsum[h * FF + t] = red[0][t] + red[1][t] + red[2][t] + red[3][t];
}

// ---------------- Kernel 5: pack adj (int 0/1) into bitmask, 1 bit per edge ----------------
__global__ __launch_bounds__(256) void k_adjpack(const int* __restrict__ adj,
                                                 unsigned* __restrict__ adjw) {
    int tid = blockIdx.x * 256 + threadIdx.x;   // over N*N
    int lane = threadIdx.x & 63;
    unsigned long long mask = __ballot(adj[tid] > 0);
    if (lane == 0) {
        int base = tid >> 5;          // tid multiple of 64 -> even word index
        adjw[base] = (unsigned)mask;
        adjw[base + 1] = (unsigned)(mask >> 32);
    }
}

// ---------------- Kernel 6: flash-style masked softmax + PV + ELU ----------------
// grid (N/64, H), block 256. 64 query rows x full F; key tiles of 64.
__global__ __launch_bounds__(256) void k_attn(const float* __restrict__ hp,
                                              const float* __restrict__ fs,
                                              const float* __restrict__ fd,
                                              const float* __restrict__ maxfd,
                                              const float* __restrict__ hpsum,
                                              const unsigned* __restrict__ adjw,
                                              float* __restrict__ outp) {
    __shared__ float wt[64 * 68];    // weights tile: 64 rows x 64 j, stride 68 (16B aligned)
    __shared__ float hpt[64 * 64];   // hp tile: 64 j x 64 f
    __shared__ float fss[64], ms[64], lacc[64];
    int t = threadIdx.x;
    int h = blockIdx.y;
    int i0 = blockIdx.x * 64;
    float mfd = maxfd[h];
    if (t < 64) {
        float fsv = fs[(size_t)h * NN + i0 + t];
        fss[t] = fsv;
        float s = fsv + mfd;
        ms[t] = s > 0.f ? s : LRELU_ALPHA * s;   // row-wise stability bound (lrelu monotone)
        lacc[t] = 0.f;
    }
    __syncthreads();

    int rg = t >> 4, fg = t & 15;
    int r0 = rg * 4, f0 = fg * 4;    // PV mapping: 4 rows x 4 f per thread
    int wr = t >> 2;                 // w-phase: row
    int jj0 = (t & 3) * 16;          // w-phase: 16 consecutive j per thread
    float acc[4][4] = {};

    for (int j0 = 0; j0 < NN; j0 += 64) {
        // Phase A: stage hp tile (64 j x 64 f)
        #pragma unroll
        for (int kidx = 0; kidx < 4; kidx++) {
            int id = t + 256 * kidx;        // 0..1023 float4s
            int j = id >> 4, f4 = id & 15;
            *(float4*)(hpt + j * 64 + f4 * 4) =
                *(const float4*)(hp + ((size_t)h * NN + j0 + j) * FF + f4 * 4);
        }
        // Phase B: compute weight tile w[r][j] = mask * exp(lrelu(fs_r+fd_j) - m_r)
        {
            unsigned word = adjw[(size_t)(i0 + wr) * (NN / 32) + ((j0 + jj0) >> 5)];
            unsigned bits = word >> (jj0 & 31);   // low 16 bits valid
            float fsr = fss[wr], mr = ms[wr];
            float part = 0.f;
            #pragma unroll
            for (int q = 0; q < 4; q++) {
                float4 fdv = *(const float4*)(fd + (size_t)h * NN + j0 + jj0 + q * 4);
                float4 wv4;
                #pragma unroll
                for (int b = 0; b < 4; b++) {
                    float s = fsr + f4c(fdv, b);
                    s = s > 0.f ? s : LRELU_ALPHA * s;
                    float e = __expf(s - mr);
                    float wvv = ((bits >> (q * 4 + b)) & 1u) ? e : 0.f;
                    f4s(wv4, b, wvv);
                    part += wvv;
                }
                *(float4*)(wt + wr * 68 + jj0 + q * 4) = wv4;
            }
            atomicAdd(&lacc[wr], part);
        }
        __syncthreads();
        // Phase C: PV accumulate — acc[r][f] += w[r][j] * hp[j][f]
        for (int jj = 0; jj < 64; jj += 4) {
            float4 wv[4], hv[4];
            #pragma unroll
            for (int i = 0; i < 4; i++) wv[i] = *(float4*)(wt + (r0 + i) * 68 + jj);
            #pragma unroll
            for (int q = 0; q < 4; q++) hv[q] = *(float4*)(hpt + (jj + q) * 64 + f0);
            #pragma unroll
            for (int i = 0; i < 4; i++) {
                #pragma unroll
                for (int q = 0; q < 4; q++) {
                    float w = f4c(wv[i], q);
                    acc[i][0] += w * f4c(hv[q], 0);
                    acc[i][1] += w * f4c(hv[q], 1);
                    acc[i][2] += w * f4c(hv[q], 2);
                    acc[i][3] += w * f4c(hv[q], 3);
                }
            }
        }
        __syncthreads();
    }

    // Epilogue: normalize, ELU, store. out[n][h*F+f]
    const float invN = 1.0f / NN;
    #pragma unroll
    for (int i = 0; i < 4; i++) {
        int r = r0 + i;
        float lr = lacc[r];
        float4 o;
        #pragma unroll
        for (int c = 0; c < 4; c++) {
            float v;
            if (lr > 0.f) v = acc[i][c] / lr;
            else          v = hpsum[h * FF + f0 + c] * invN;   // all-masked row: uniform softmax
            f4s(o, c, v > 0.f ? v : __expf(v) - 1.f);
        }
        *(float4*)(outp + (size_t)(i0 + r) * (HH * FF) + h * FF + f0) = o;
    }
}

extern "C" void kernel_launch(void* const* d_in, const int* in_sizes, int n_in,
                              void* d_out, int out_size, void* d_ws, size_t ws_size,
                              hipStream_t stream) {
    const float* hmat = (const float*)d_in[0];
    const int*   adj  = (const int*)d_in[1];
    const float* W    = (const float*)d_in[2];
    const float* a    = (const float*)d_in[3];
    float* out = (float*)d_out;

    float* hp    = (float*)d_ws;                       // H*N*F = 2,097,152 floats
    float* fs    = hp + (size_t)HH * NN * FF;          // H*N
    float* fd    = fs + (size_t)HH * NN;               // H*N
    float* mxfd  = fd + (size_t)HH * NN;               // H
    float* hpsum = mxfd + 8;                           // H*F
    unsigned* adjw = (unsigned*)(hpsum + 512);         // N*N/32 words (2 MB)

    k_hp   <<<dim3(NN / 64, HH), 256, 0, stream>>>(hmat, W, hp);
    k_fsfd <<<dim3(HH * NN / 4), 256, 0, stream>>>(hp, a, fs, fd);
    k_maxfd<<<dim3(HH),          256, 0, stream>>>(fd, mxfd);
    k_hpsum<<<dim3(HH),          256, 0, stream>>>(hp, hpsum);
    k_adjpack<<<dim3(NN * NN / 256), 256, 0, stream>>>(adj, adjw);
    k_attn <<<dim3(NN / 64, HH), 256, 0, stream>>>(hp, fs, fd, mxfd, hpsum, adjw, out);
}

// Round 2
// 509.780 us; speedup vs baseline: 1.3476x; 1.3476x over previous
//
#include <hip/hip_runtime.h>

#define NN 4096
#define DD 512
#define HH 8
#define FF 64
#define LRELU_ALPHA 0.2f
#define SP 72   // LDS row stride in bf16 elems (144B: 16B-aligned, ~uniform bank spread)

typedef __attribute__((ext_vector_type(8))) short bf16x8;
typedef __attribute__((ext_vector_type(4))) float f32x4;

__device__ __forceinline__ float f4c(const float4& v, int k) {
    return k == 0 ? v.x : (k == 1 ? v.y : (k == 2 ? v.z : v.w));
}
__device__ __forceinline__ void f4s(float4& v, int k, float x) {
    if (k == 0) v.x = x; else if (k == 1) v.y = x; else if (k == 2) v.z = x; else v.w = x;
}
__device__ __forceinline__ unsigned short f2bf(float x) {   // RNE float->bf16
    unsigned u = __float_as_uint(x);
    return (unsigned short)((u + 0x7fffu + ((u >> 16) & 1u)) >> 16);
}
__device__ __forceinline__ float bf2f(unsigned short h) {
    return __uint_as_float(((unsigned)h) << 16);
}

// ---------------- Kernel 1: hp[h][n][f] = sum_d h[n][d] * W[h][d][f] ----------------
__global__ __launch_bounds__(256) void k_hp(const float* __restrict__ hmat,
                                            const float* __restrict__ W,
                                            float* __restrict__ hp) {
    __shared__ float ht[64 * 36];
    __shared__ float wt[32 * 64];
    int t = threadIdx.x;
    int hz = blockIdx.y;
    int r0b = blockIdx.x * 64;
    int rg = t >> 4, fg = t & 15;
    int r0 = rg * 4, f0 = fg * 4;
    float acc[4][4] = {};
    for (int kk = 0; kk < DD; kk += 32) {
        #pragma unroll
        for (int ii = 0; ii < 2; ii++) {
            int id = t * 2 + ii;
            int row = id >> 3, k4 = id & 7;
            float4 v = *(const float4*)(hmat + (size_t)(r0b + row) * DD + kk + k4 * 4);
            float* d = ht + row * 36 + k4 * 4;
            d[0] = v.x; d[1] = v.y; d[2] = v.z; d[3] = v.w;
        }
        #pragma unroll
        for (int ii = 0; ii < 2; ii++) {
            int id = t * 2 + ii;
            int k = id >> 4, f4 = id & 15;
            *(float4*)(wt + k * 64 + f4 * 4) =
                *(const float4*)(W + ((size_t)hz * DD + kk + k) * FF + f4 * 4);
        }
        __syncthreads();
        #pragma unroll
        for (int k = 0; k < 32; k++) {
            float a0 = ht[(r0 + 0) * 36 + k];
            float a1 = ht[(r0 + 1) * 36 + k];
            float a2 = ht[(r0 + 2) * 36 + k];
            float a3 = ht[(r0 + 3) * 36 + k];
            float4 b = *(float4*)(wt + k * 64 + f0);
            acc[0][0] += a0 * b.x; acc[0][1] += a0 * b.y; acc[0][2] += a0 * b.z; acc[0][3] += a0 * b.w;
            acc[1][0] += a1 * b.x; acc[1][1] += a1 * b.y; acc[1][2] += a1 * b.z; acc[1][3] += a1 * b.w;
            acc[2][0] += a2 * b.x; acc[2][1] += a2 * b.y; acc[2][2] += a2 * b.z; acc[2][3] += a2 * b.w;
            acc[3][0] += a3 * b.x; acc[3][1] += a3 * b.y; acc[3][2] += a3 * b.z; acc[3][3] += a3 * b.w;
        }
        __syncthreads();
    }
    #pragma unroll
    for (int i = 0; i < 4; i++) {
        float4 o; o.x = acc[i][0]; o.y = acc[i][1]; o.z = acc[i][2]; o.w = acc[i][3];
        *(float4*)(hp + ((size_t)hz * NN + r0b + r0 + i) * FF + f0) = o;
    }
}

// ---------------- Kernel 1b: split hp into bf16 hi/lo, transposed to [h][f][n] ----------------
__global__ __launch_bounds__(256) void k_hpsplit(const float* __restrict__ hp,
                                                 unsigned short* __restrict__ hpT_hi,
                                                 unsigned short* __restrict__ hpT_lo) {
    __shared__ float tile[64][65];
    int t = threadIdx.x;
    int h = blockIdx.y;
    int n0 = blockIdx.x * 64;
    #pragma unroll
    for (int kidx = 0; kidx < 4; kidx++) {
        int id = t + 256 * kidx;          // 0..1023 float4s
        int n = id >> 4, f4 = (id & 15) * 4;
        float4 v = *(const float4*)(hp + ((size_t)h * NN + n0 + n) * FF + f4);
        tile[n][f4 + 0] = v.x; tile[n][f4 + 1] = v.y; tile[n][f4 + 2] = v.z; tile[n][f4 + 3] = v.w;
    }
    __syncthreads();
    int f = t >> 2, c = (t & 3) * 16;
    union { unsigned short s[16]; uint4 v[2]; } hb, lb;
    #pragma unroll
    for (int q = 0; q < 16; q++) {
        float v = tile[c + q][f];
        unsigned short hi = f2bf(v);
        hb.s[q] = hi;
        lb.s[q] = f2bf(v - bf2f(hi));
    }
    uint4* dh = (uint4*)(hpT_hi + ((size_t)h * FF + f) * NN + n0 + c);
    uint4* dl = (uint4*)(hpT_lo + ((size_t)h * FF + f) * NN + n0 + c);
    dh[0] = hb.v[0]; dh[1] = hb.v[1];
    dl[0] = lb.v[0]; dl[1] = lb.v[1];
}

// ---------------- Kernel 2: fs/fd = hp . a_src / a_dst ----------------
__global__ __launch_bounds__(256) void k_fsfd(const float* __restrict__ hp,
                                              const float* __restrict__ a,
                                              float* __restrict__ fs, float* __restrict__ fd) {
    int t = threadIdx.x;
    int gw = blockIdx.x * 4 + (t >> 6);
    int h = gw >> 12;
    int n = gw & (NN - 1);
    int f = t & 63;
    float v = hp[((size_t)h * NN + n) * FF + f];
    float vs = v * a[h * 2 * FF + f];
    float vd = v * a[h * 2 * FF + FF + f];
    #pragma unroll
    for (int off = 32; off; off >>= 1) {
        vs += __shfl_xor(vs, off);
        vd += __shfl_xor(vd, off);
    }
    if (f == 0) { fs[(size_t)h * NN + n] = vs; fd[(size_t)h * NN + n] = vd; }
}

// ---------------- Kernel 3: maxfd[h] = max_n fd[h][n] ----------------
__global__ __launch_bounds__(256) void k_maxfd(const float* __restrict__ fd,
                                               float* __restrict__ maxfd) {
    __shared__ float red[256];
    int h = blockIdx.x, t = threadIdx.x;
    float m = -1e30f;
    for (int n = t; n < NN; n += 256) m = fmaxf(m, fd[(size_t)h * NN + n]);
    red[t] = m;
    __syncthreads();
    for (int s = 128; s; s >>= 1) {
        if (t < s) red[t] = fmaxf(red[t], red[t + s]);
        __syncthreads();
    }
    if (t == 0) maxfd[h] = red[0];
}

// ---------------- Kernel 4: hpsum[h][f] = sum_n hp[h][n][f] ----------------
__global__ __launch_bounds__(256) void k_hpsum(const float* __restrict__ hp,
                                               float* __restrict__ hpsum) {
    __shared__ float red[4][64];
    int h = blockIdx.x, t = threadIdx.x;
    int f = t & 63, part = t >> 6;
    float s = 0.f;
    for (int n = part; n < NN; n += 4) s += hp[((size_t)h * NN + n) * FF + f];
    red[part][f] = s;
    __syncthreads();
    if (t < 64) hpsum[h * FF + t] = red[0][t] + red[1][t] + red[2][t] + red[3][t];
}

// ---------------- Kernel 5: pack adj into bitmask ----------------
__global__ __launch_bounds__(256) void k_adjpack(const int* __restrict__ adj,
                                                 unsigned* __restrict__ adjw) {
    int tid = blockIdx.x * 256 + threadIdx.x;
    int lane = threadIdx.x & 63;
    unsigned long long mask = __ballot(adj[tid] > 0);
    if (lane == 0) {
        int base = tid >> 5;
        adjw[base] = (unsigned)mask;
        adjw[base + 1] = (unsigned)(mask >> 32);
    }
}

// ---------------- Kernel 6: masked softmax weights (VALU) + PV (bf16 MFMA, hp split hi/lo) ----
// grid (N/64, H), block 256 (4 waves). Each wave owns a 32x32 output quadrant.
__global__ __launch_bounds__(256) void k_attn(const float* __restrict__ fs,
                                              const float* __restrict__ fd,
                                              const float* __restrict__ maxfd,
                                              const float* __restrict__ hpsum,
                                              const unsigned* __restrict__ adjw,
                                              const unsigned short* __restrict__ hpT_hi,
                                              const unsigned short* __restrict__ hpT_lo,
                                              float* __restrict__ outp) {
    __shared__ unsigned short pa[64 * SP];    // P tile (bf16), rows = q, k-contig
    __shared__ unsigned short hbh[64 * SP];   // hpT hi tile, rows = f, k-contig (j)
    __shared__ unsigned short hbl[64 * SP];   // hpT lo tile
    __shared__ float fss[64], ms[64], lacc[64];

    int t = threadIdx.x;
    int h = blockIdx.y;
    int i0 = blockIdx.x * 64;
    int lane = t & 63;
    int w = t >> 6;

    float mfd = maxfd[h];
    if (t < 64) {
        float fsv = fs[(size_t)h * NN + i0 + t];
        fss[t] = fsv;
        float s = fsv + mfd;
        ms[t] = s > 0.f ? s : LRELU_ALPHA * s;   // valid upper bound (lrelu monotone)
    }
    __syncthreads();

    int wr = t >> 2;            // staging/weight row 0..63
    int wc = (t & 3) * 16;      // 16-wide chunk
    int R0 = (w >> 1) * 32, F0 = (w & 1) * 32;   // wave's output quadrant
    int am = lane & 15, aq = lane >> 4;          // MFMA fragment indices
    float lsum = 0.f;
    f32x4 acc[2][2] = {};

    const unsigned short* gH = hpT_hi + (size_t)h * FF * NN;
    const unsigned short* gL = hpT_lo + (size_t)h * FF * NN;
    const float* fdh = fd + (size_t)h * NN;

    for (int j0 = 0; j0 < NN; j0 += 64) {
        // Phase A: stage hpT hi/lo tiles (f=wr, 16 j per thread = 32B each)
        {
            const uint4* sh = (const uint4*)(gH + (size_t)wr * NN + j0 + wc);
            const uint4* sl = (const uint4*)(gL + (size_t)wr * NN + j0 + wc);
            uint4 v0 = sh[0], v1 = sh[1];
            uint4 u0 = sl[0], u1 = sl[1];
            *(uint4*)(hbh + wr * SP + wc) = v0;
            *(uint4*)(hbh + wr * SP + wc + 8) = v1;
            *(uint4*)(hbl + wr * SP + wc) = u0;
            *(uint4*)(hbl + wr * SP + wc + 8) = u1;
        }
        // Phase B: weights w[r][j] = mask * exp(lrelu(fs_r+fd_j) - m_r), bf16 into pa
        {
            unsigned word = adjw[(size_t)(i0 + wr) * (NN / 32) + ((j0 + wc) >> 5)];
            unsigned bits = word >> (wc & 31);
            float fsr = fss[wr], mr = ms[wr];
            float part = 0.f;
            union { unsigned short s[16]; uint4 v[2]; } wb;
            #pragma unroll
            for (int q = 0; q < 4; q++) {
                float4 fdv = *(const float4*)(fdh + j0 + wc + q * 4);
                #pragma unroll
                for (int b = 0; b < 4; b++) {
                    float s = fsr + f4c(fdv, b);
                    s = s > 0.f ? s : LRELU_ALPHA * s;
                    float e = __expf(s - mr);
                    e = ((bits >> (q * 4 + b)) & 1u) ? e : 0.f;
                    part += e;
                    wb.s[q * 4 + b] = f2bf(e);
                }
            }
            *(uint4*)(pa + wr * SP + wc) = wb.v[0];
            *(uint4*)(pa + wr * SP + wc + 8) = wb.v[1];
            part += __shfl_xor(part, 1);
            part += __shfl_xor(part, 2);
            if ((t & 3) == 0) lsum += part;
        }
        __syncthreads();
        // Phase C: MFMA — acc[m][n] += P * (hi+lo)
        #pragma unroll
        for (int k2 = 0; k2 < 2; k2++) {
            int ko = k2 * 32 + aq * 8;
            bf16x8 a0  = *(const bf16x8*)(pa  + (R0 + am) * SP + ko);
            bf16x8 a1  = *(const bf16x8*)(pa  + (R0 + 16 + am) * SP + ko);
            bf16x8 b0h = *(const bf16x8*)(hbh + (F0 + am) * SP + ko);
            bf16x8 b1h = *(const bf16x8*)(hbh + (F0 + 16 + am) * SP + ko);
            bf16x8 b0l = *(const bf16x8*)(hbl + (F0 + am) * SP + ko);
            bf16x8 b1l = *(const bf16x8*)(hbl + (F0 + 16 + am) * SP + ko);
            acc[0][0] = __builtin_amdgcn_mfma_f32_16x16x32_bf16(a0, b0h, acc[0][0], 0, 0, 0);
            acc[0][1] = __builtin_amdgcn_mfma_f32_16x16x32_bf16(a0, b1h, acc[0][1], 0, 0, 0);
            acc[1][0] = __builtin_amdgcn_mfma_f32_16x16x32_bf16(a1, b0h, acc[1][0], 0, 0, 0);
            acc[1][1] = __builtin_amdgcn_mfma_f32_16x16x32_bf16(a1, b1h, acc[1][1], 0, 0, 0);
            acc[0][0] = __builtin_amdgcn_mfma_f32_16x16x32_bf16(a0, b0l, acc[0][0], 0, 0, 0);
            acc[0][1] = __builtin_amdgcn_mfma_f32_16x16x32_bf16(a0, b1l, acc[0][1], 0, 0, 0);
            acc[1][0] = __builtin_amdgcn_mfma_f32_16x16x32_bf16(a1, b0l, acc[1][0], 0, 0, 0);
            acc[1][1] = __builtin_amdgcn_mfma_f32_16x16x32_bf16(a1, b1l, acc[1][1], 0, 0, 0);
        }
        __syncthreads();
    }

    if ((t & 3) == 0) lacc[wr] = lsum;
    __syncthreads();

    // Epilogue: C/D layout col=lane&15, row=(lane>>4)*4+reg (guide-verified m89)
    const float invN = 1.0f / NN;
    int col = lane & 15, rbase = (lane >> 4) * 4;
    #pragma unroll
    for (int m16 = 0; m16 < 2; m16++) {
        #pragma unroll
        for (int n16 = 0; n16 < 2; n16++) {
            #pragma unroll
            for (int r = 0; r < 4; r++) {
                int row = R0 + m16 * 16 + rbase + r;
                int f = F0 + n16 * 16 + col;
                float l = lacc[row];
                float v = (l > 0.f) ? acc[m16][n16][r] / l
                                    : hpsum[h * FF + f] * invN;   // all-masked row
                v = v > 0.f ? v : __expf(v) - 1.f;
                outp[(size_t)(i0 + row) * (HH * FF) + h * FF + f] = v;
            }
        }
    }
}

extern "C" void kernel_launch(void* const* d_in, const int* in_sizes, int n_in,
                              void* d_out, int out_size, void* d_ws, size_t ws_size,
                              hipStream_t stream) {
    const float* hmat = (const float*)d_in[0];
    const int*   adj  = (const int*)d_in[1];
    const float* W    = (const float*)d_in[2];
    const float* a    = (const float*)d_in[3];
    float* out = (float*)d_out;

    float* hp    = (float*)d_ws;                        // H*N*F floats (8 MB)
    float* fs    = hp + (size_t)HH * NN * FF;           // H*N
    float* fd    = fs + (size_t)HH * NN;                // H*N
    float* mxfd  = fd + (size_t)HH * NN;                // 8
    float* hpsum = mxfd + 8;                            // H*F
    unsigned* adjw = (unsigned*)(hpsum + 512);          // N*N/32 (2 MB)
    unsigned short* hpT_hi = (unsigned short*)(adjw + (size_t)NN * NN / 32);  // 4 MB
    unsigned short* hpT_lo = hpT_hi + (size_t)HH * FF * NN;                   // 4 MB

    k_hp     <<<dim3(NN / 64, HH), 256, 0, stream>>>(hmat, W, hp);
    k_hpsplit<<<dim3(NN / 64, HH), 256, 0, stream>>>(hp, hpT_hi, hpT_lo);
    k_fsfd   <<<dim3(HH * NN / 4), 256, 0, stream>>>(hp, a, fs, fd);
    k_maxfd  <<<dim3(HH),          256, 0, stream>>>(fd, mxfd);
    k_hpsum  <<<dim3(HH),          256, 0, stream>>>(hp, hpsum);
    k_adjpack<<<dim3(NN * NN / 256), 256, 0, stream>>>(adj, adjw);
    k_attn   <<<dim3(NN / 64, HH), 256, 0, stream>>>(fs, fd, mxfd, hpsum, adjw,
                                                     hpT_hi, hpT_lo, out);
}

// Round 3
// 339.340 us; speedup vs baseline: 2.0244x; 1.5023x over previous
//
#include <hip/hip_runtime.h>

#define NN 4096
#define DD 512
#define HH 8
#define FF 64
#define LRELU_ALPHA 0.2f
#define SP 72   // LDS row stride in bf16 elems (144B: 16B-aligned, ~uniform bank spread)

typedef __attribute__((ext_vector_type(8))) short bf16x8;
typedef __attribute__((ext_vector_type(4))) float f32x4;

__device__ __forceinline__ float f4c(const float4& v, int k) {
    return k == 0 ? v.x : (k == 1 ? v.y : (k == 2 ? v.z : v.w));
}
__device__ __forceinline__ void f4s(float4& v, int k, float x) {
    if (k == 0) v.x = x; else if (k == 1) v.y = x; else if (k == 2) v.z = x; else v.w = x;
}
__device__ __forceinline__ unsigned short f2bf(float x) {   // RNE float->bf16
    unsigned u = __float_as_uint(x);
    return (unsigned short)((u + 0x7fffu + ((u >> 16) & 1u)) >> 16);
}
__device__ __forceinline__ float bf2f(unsigned short h) {
    return __uint_as_float(((unsigned)h) << 16);
}

// ---------------- Kernel 1: hp[h][n][f] = sum_d h[n][d] * W[h][d][f] ----------------
__global__ __launch_bounds__(256) void k_hp(const float* __restrict__ hmat,
                                            const float* __restrict__ W,
                                            float* __restrict__ hp) {
    __shared__ float ht[64 * 36];
    __shared__ float wt[32 * 64];
    int t = threadIdx.x;
    int hz = blockIdx.y;
    int r0b = blockIdx.x * 64;
    int rg = t >> 4, fg = t & 15;
    int r0 = rg * 4, f0 = fg * 4;
    float acc[4][4] = {};
    for (int kk = 0; kk < DD; kk += 32) {
        #pragma unroll
        for (int ii = 0; ii < 2; ii++) {
            int id = t * 2 + ii;
            int row = id >> 3, k4 = id & 7;
            float4 v = *(const float4*)(hmat + (size_t)(r0b + row) * DD + kk + k4 * 4);
            float* d = ht + row * 36 + k4 * 4;
            d[0] = v.x; d[1] = v.y; d[2] = v.z; d[3] = v.w;
        }
        #pragma unroll
        for (int ii = 0; ii < 2; ii++) {
            int id = t * 2 + ii;
            int k = id >> 4, f4 = id & 15;
            *(float4*)(wt + k * 64 + f4 * 4) =
                *(const float4*)(W + ((size_t)hz * DD + kk + k) * FF + f4 * 4);
        }
        __syncthreads();
        #pragma unroll
        for (int k = 0; k < 32; k++) {
            float a0 = ht[(r0 + 0) * 36 + k];
            float a1 = ht[(r0 + 1) * 36 + k];
            float a2 = ht[(r0 + 2) * 36 + k];
            float a3 = ht[(r0 + 3) * 36 + k];
            float4 b = *(float4*)(wt + k * 64 + f0);
            acc[0][0] += a0 * b.x; acc[0][1] += a0 * b.y; acc[0][2] += a0 * b.z; acc[0][3] += a0 * b.w;
            acc[1][0] += a1 * b.x; acc[1][1] += a1 * b.y; acc[1][2] += a1 * b.z; acc[1][3] += a1 * b.w;
            acc[2][0] += a2 * b.x; acc[2][1] += a2 * b.y; acc[2][2] += a2 * b.z; acc[2][3] += a2 * b.w;
            acc[3][0] += a3 * b.x; acc[3][1] += a3 * b.y; acc[3][2] += a3 * b.z; acc[3][3] += a3 * b.w;
        }
        __syncthreads();
    }
    #pragma unroll
    for (int i = 0; i < 4; i++) {
        float4 o; o.x = acc[i][0]; o.y = acc[i][1]; o.z = acc[i][2]; o.w = acc[i][3];
        *(float4*)(hp + ((size_t)hz * NN + r0b + r0 + i) * FF + f0) = o;
    }
}

// ---------------- Kernel 1b: split hp into bf16 hi/lo, transposed to [h][f][n] ----------------
__global__ __launch_bounds__(256) void k_hpsplit(const float* __restrict__ hp,
                                                 unsigned short* __restrict__ hpT_hi,
                                                 unsigned short* __restrict__ hpT_lo) {
    __shared__ float tile[64][65];
    int t = threadIdx.x;
    int h = blockIdx.y;
    int n0 = blockIdx.x * 64;
    #pragma unroll
    for (int kidx = 0; kidx < 4; kidx++) {
        int id = t + 256 * kidx;          // 0..1023 float4s
        int n = id >> 4, f4 = (id & 15) * 4;
        float4 v = *(const float4*)(hp + ((size_t)h * NN + n0 + n) * FF + f4);
        tile[n][f4 + 0] = v.x; tile[n][f4 + 1] = v.y; tile[n][f4 + 2] = v.z; tile[n][f4 + 3] = v.w;
    }
    __syncthreads();
    int f = t >> 2, c = (t & 3) * 16;
    union { unsigned short s[16]; uint4 v[2]; } hb, lb;
    #pragma unroll
    for (int q = 0; q < 16; q++) {
        float v = tile[c + q][f];
        unsigned short hi = f2bf(v);
        hb.s[q] = hi;
        lb.s[q] = f2bf(v - bf2f(hi));
    }
    uint4* dh = (uint4*)(hpT_hi + ((size_t)h * FF + f) * NN + n0 + c);
    uint4* dl = (uint4*)(hpT_lo + ((size_t)h * FF + f) * NN + n0 + c);
    dh[0] = hb.v[0]; dh[1] = hb.v[1];
    dl[0] = lb.v[0]; dl[1] = lb.v[1];
}

// ---------------- Kernel 2: fs/fd = hp . a_src / a_dst ----------------
__global__ __launch_bounds__(256) void k_fsfd(const float* __restrict__ hp,
                                              const float* __restrict__ a,
                                              float* __restrict__ fs, float* __restrict__ fd) {
    int t = threadIdx.x;
    int gw = blockIdx.x * 4 + (t >> 6);
    int h = gw >> 12;
    int n = gw & (NN - 1);
    int f = t & 63;
    float v = hp[((size_t)h * NN + n) * FF + f];
    float vs = v * a[h * 2 * FF + f];
    float vd = v * a[h * 2 * FF + FF + f];
    #pragma unroll
    for (int off = 32; off; off >>= 1) {
        vs += __shfl_xor(vs, off);
        vd += __shfl_xor(vd, off);
    }
    if (f == 0) { fs[(size_t)h * NN + n] = vs; fd[(size_t)h * NN + n] = vd; }
}

// ---------------- Kernel 3: maxfd[h] = max_n fd[h][n] ----------------
__global__ __launch_bounds__(256) void k_maxfd(const float* __restrict__ fd,
                                               float* __restrict__ maxfd) {
    __shared__ float red[256];
    int h = blockIdx.x, t = threadIdx.x;
    float m = -1e30f;
    for (int n = t; n < NN; n += 256) m = fmaxf(m, fd[(size_t)h * NN + n]);
    red[t] = m;
    __syncthreads();
    for (int s = 128; s; s >>= 1) {
        if (t < s) red[t] = fmaxf(red[t], red[t + s]);
        __syncthreads();
    }
    if (t == 0) maxfd[h] = red[0];
}

// ---------------- Kernel 4a: column-sum of h -> partial[64][512] ----------------
// hpsum[h][f] = (sum_n h[n][:]) @ W[h] ; stage 1: 64 blocks x 64 rows each, coalesced.
__global__ __launch_bounds__(256) void k_colsum(const float* __restrict__ hmat,
                                                float* __restrict__ partial) {
    int b = blockIdx.x, t = threadIdx.x;
    const float* base = hmat + (size_t)b * 64 * DD;
    float s0 = 0.f, s1 = 0.f;
    #pragma unroll 8
    for (int r = 0; r < 64; r++) {
        float2 v = *(const float2*)(base + (size_t)r * DD + t * 2);
        s0 += v.x; s1 += v.y;
    }
    partial[b * DD + t * 2] = s0;
    partial[b * DD + t * 2 + 1] = s1;
}

// ---------------- Kernel 4b: hpsum[h][f] = hsum . W[h][:][f] ----------------
__global__ __launch_bounds__(256) void k_hpsumW(const float* __restrict__ partial,
                                                const float* __restrict__ W,
                                                float* __restrict__ hpsum) {
    __shared__ float hsum[DD];
    int h = blockIdx.x, t = threadIdx.x;
    for (int d = t; d < DD; d += 256) {
        float s = 0.f;
        #pragma unroll 8
        for (int p = 0; p < 64; p++) s += partial[p * DD + d];
        hsum[d] = s;
    }
    __syncthreads();
    int f = t >> 2, part = t & 3;
    float s = 0.f;
    for (int d = part; d < DD; d += 4) s += hsum[d] * W[((size_t)h * DD + d) * FF + f];
    s += __shfl_xor(s, 1);
    s += __shfl_xor(s, 2);
    if (part == 0) hpsum[h * FF + f] = s;
}

// ---------------- Kernel 5: pack adj into bitmask ----------------
__global__ __launch_bounds__(256) void k_adjpack(const int* __restrict__ adj,
                                                 unsigned* __restrict__ adjw) {
    int tid = blockIdx.x * 256 + threadIdx.x;
    int lane = threadIdx.x & 63;
    unsigned long long mask = __ballot(adj[tid] > 0);
    if (lane == 0) {
        int base = tid >> 5;
        adjw[base] = (unsigned)mask;
        adjw[base + 1] = (unsigned)(mask >> 32);
    }
}

// ---------------- Kernel 6: masked softmax weights (VALU) + PV (bf16 MFMA, hp split hi/lo) ----
__global__ __launch_bounds__(256) void k_attn(const float* __restrict__ fs,
                                              const float* __restrict__ fd,
                                              const float* __restrict__ maxfd,
                                              const float* __restrict__ hpsum,
                                              const unsigned* __restrict__ adjw,
                                              const unsigned short* __restrict__ hpT_hi,
                                              const unsigned short* __restrict__ hpT_lo,
                                              float* __restrict__ outp) {
    __shared__ unsigned short pa[64 * SP];    // P tile (bf16), rows = q, k-contig
    __shared__ unsigned short hbh[64 * SP];   // hpT hi tile, rows = f, k-contig (j)
    __shared__ unsigned short hbl[64 * SP];   // hpT lo tile
    __shared__ float fss[64], ms[64], lacc[64];

    int t = threadIdx.x;
    int h = blockIdx.y;
    int i0 = blockIdx.x * 64;
    int lane = t & 63;
    int w = t >> 6;

    float mfd = maxfd[h];
    if (t < 64) {
        float fsv = fs[(size_t)h * NN + i0 + t];
        fss[t] = fsv;
        float s = fsv + mfd;
        ms[t] = s > 0.f ? s : LRELU_ALPHA * s;   // valid upper bound (lrelu monotone)
    }
    __syncthreads();

    int wr = t >> 2;            // staging/weight row 0..63
    int wc = (t & 3) * 16;      // 16-wide chunk
    int R0 = (w >> 1) * 32, F0 = (w & 1) * 32;   // wave's output quadrant
    int am = lane & 15, aq = lane >> 4;          // MFMA fragment indices
    float lsum = 0.f;
    f32x4 acc[2][2] = {};

    const unsigned short* gH = hpT_hi + (size_t)h * FF * NN;
    const unsigned short* gL = hpT_lo + (size_t)h * FF * NN;
    const float* fdh = fd + (size_t)h * NN;

    for (int j0 = 0; j0 < NN; j0 += 64) {
        // Phase A: stage hpT hi/lo tiles (f=wr, 16 j per thread = 32B each)
        {
            const uint4* sh = (const uint4*)(gH + (size_t)wr * NN + j0 + wc);
            const uint4* sl = (const uint4*)(gL + (size_t)wr * NN + j0 + wc);
            uint4 v0 = sh[0], v1 = sh[1];
            uint4 u0 = sl[0], u1 = sl[1];
            *(uint4*)(hbh + wr * SP + wc) = v0;
            *(uint4*)(hbh + wr * SP + wc + 8) = v1;
            *(uint4*)(hbl + wr * SP + wc) = u0;
            *(uint4*)(hbl + wr * SP + wc + 8) = u1;
        }
        // Phase B: weights w[r][j] = mask * exp(lrelu(fs_r+fd_j) - m_r), bf16 into pa
        {
            unsigned word = adjw[(size_t)(i0 + wr) * (NN / 32) + ((j0 + wc) >> 5)];
            unsigned bits = word >> (wc & 31);
            float fsr = fss[wr], mr = ms[wr];
            float part = 0.f;
            union { unsigned short s[16]; uint4 v[2]; } wb;
            #pragma unroll
            for (int q = 0; q < 4; q++) {
                float4 fdv = *(const float4*)(fdh + j0 + wc + q * 4);
                #pragma unroll
                for (int b = 0; b < 4; b++) {
                    float s = fsr + f4c(fdv, b);
                    s = s > 0.f ? s : LRELU_ALPHA * s;
                    float e = __expf(s - mr);
                    e = ((bits >> (q * 4 + b)) & 1u) ? e : 0.f;
                    part += e;
                    wb.s[q * 4 + b] = f2bf(e);
                }
            }
            *(uint4*)(pa + wr * SP + wc) = wb.v[0];
            *(uint4*)(pa + wr * SP + wc + 8) = wb.v[1];
            part += __shfl_xor(part, 1);
            part += __shfl_xor(part, 2);
            if ((t & 3) == 0) lsum += part;
        }
        __syncthreads();
        // Phase C: MFMA — acc[m][n] += P * (hi+lo)
        #pragma unroll
        for (int k2 = 0; k2 < 2; k2++) {
            int ko = k2 * 32 + aq * 8;
            bf16x8 a0  = *(const bf16x8*)(pa  + (R0 + am) * SP + ko);
            bf16x8 a1  = *(const bf16x8*)(pa  + (R0 + 16 + am) * SP + ko);
            bf16x8 b0h = *(const bf16x8*)(hbh + (F0 + am) * SP + ko);
            bf16x8 b1h = *(const bf16x8*)(hbh + (F0 + 16 + am) * SP + ko);
            bf16x8 b0l = *(const bf16x8*)(hbl + (F0 + am) * SP + ko);
            bf16x8 b1l = *(const bf16x8*)(hbl + (F0 + 16 + am) * SP + ko);
            acc[0][0] = __builtin_amdgcn_mfma_f32_16x16x32_bf16(a0, b0h, acc[0][0], 0, 0, 0);
            acc[0][1] = __builtin_amdgcn_mfma_f32_16x16x32_bf16(a0, b1h, acc[0][1], 0, 0, 0);
            acc[1][0] = __builtin_amdgcn_mfma_f32_16x16x32_bf16(a1, b0h, acc[1][0], 0, 0, 0);
            acc[1][1] = __builtin_amdgcn_mfma_f32_16x16x32_bf16(a1, b1h, acc[1][1], 0, 0, 0);
            acc[0][0] = __builtin_amdgcn_mfma_f32_16x16x32_bf16(a0, b0l, acc[0][0], 0, 0, 0);
            acc[0][1] = __builtin_amdgcn_mfma_f32_16x16x32_bf16(a0, b1l, acc[0][1], 0, 0, 0);
            acc[1][0] = __builtin_amdgcn_mfma_f32_16x16x32_bf16(a1, b0l, acc[1][0], 0, 0, 0);
            acc[1][1] = __builtin_amdgcn_mfma_f32_16x16x32_bf16(a1, b1l, acc[1][1], 0, 0, 0);
        }
        __syncthreads();
    }

    if ((t & 3) == 0) lacc[wr] = lsum;
    __syncthreads();

    // Epilogue: C/D layout col=lane&15, row=(lane>>4)*4+reg (guide-verified m89)
    const float invN = 1.0f / NN;
    int col = lane & 15, rbase = (lane >> 4) * 4;
    #pragma unroll
    for (int m16 = 0; m16 < 2; m16++) {
        #pragma unroll
        for (int n16 = 0; n16 < 2; n16++) {
            #pragma unroll
            for (int r = 0; r < 4; r++) {
                int row = R0 + m16 * 16 + rbase + r;
                int f = F0 + n16 * 16 + col;
                float l = lacc[row];
                float v = (l > 0.f) ? acc[m16][n16][r] / l
                                    : hpsum[h * FF + f] * invN;   // all-masked row
                v = v > 0.f ? v : __expf(v) - 1.f;
                outp[(size_t)(i0 + row) * (HH * FF) + h * FF + f] = v;
            }
        }
    }
}

extern "C" void kernel_launch(void* const* d_in, const int* in_sizes, int n_in,
                              void* d_out, int out_size, void* d_ws, size_t ws_size,
                              hipStream_t stream) {
    const float* hmat = (const float*)d_in[0];
    const int*   adj  = (const int*)d_in[1];
    const float* W    = (const float*)d_in[2];
    const float* a    = (const float*)d_in[3];
    float* out = (float*)d_out;

    float* hp    = (float*)d_ws;                        // H*N*F floats (8 MB)
    float* fs    = hp + (size_t)HH * NN * FF;           // H*N
    float* fd    = fs + (size_t)HH * NN;                // H*N
    float* mxfd  = fd + (size_t)HH * NN;                // 8
    float* hpsum = mxfd + 8;                            // H*F
    unsigned* adjw = (unsigned*)(hpsum + 512);          // N*N/32 (2 MB)
    unsigned short* hpT_hi = (unsigned short*)(adjw + (size_t)NN * NN / 32);  // 4 MB
    unsigned short* hpT_lo = hpT_hi + (size_t)HH * FF * NN;                   // 4 MB
    float* colpart = (float*)(hpT_lo + (size_t)HH * FF * NN);                 // 64*512 floats

    k_hp     <<<dim3(NN / 64, HH), 256, 0, stream>>>(hmat, W, hp);
    k_hpsplit<<<dim3(NN / 64, HH), 256, 0, stream>>>(hp, hpT_hi, hpT_lo);
    k_fsfd   <<<dim3(HH * NN / 4), 256, 0, stream>>>(hp, a, fs, fd);
    k_maxfd  <<<dim3(HH),          256, 0, stream>>>(fd, mxfd);
    k_colsum <<<dim3(64),          256, 0, stream>>>(hmat, colpart);
    k_hpsumW <<<dim3(HH),          256, 0, stream>>>(colpart, W, hpsum);
    k_adjpack<<<dim3(NN * NN / 256), 256, 0, stream>>>(adj, adjw);
    k_attn   <<<dim3(NN / 64, HH), 256, 0, stream>>>(fs, fd, mxfd, hpsum, adjw,
                                                     hpT_hi, hpT_lo, out);
}

// Round 5
// 271.208 us; speedup vs baseline: 2.5330x; 1.2512x over previous
//
#include <hip/hip_runtime.h>

#define NN 4096
#define DD 512
#define HH 8
#define FF 64
#define LRELU_ALPHA 0.2f
#define SP 72   // LDS row stride in bf16 elems

typedef __attribute__((ext_vector_type(8))) short bf16x8;
typedef __attribute__((ext_vector_type(4))) float f32x4;

__device__ __forceinline__ float f4c(const float4& v, int k) {
    return k == 0 ? v.x : (k == 1 ? v.y : (k == 2 ? v.z : v.w));
}
__device__ __forceinline__ void f4s(float4& v, int k, float x) {
    if (k == 0) v.x = x; else if (k == 1) v.y = x; else if (k == 2) v.z = x; else v.w = x;
}
__device__ __forceinline__ unsigned short f2bf(float x) {   // RNE float->bf16
    unsigned u = __float_as_uint(x);
    return (unsigned short)((u + 0x7fffu + ((u >> 16) & 1u)) >> 16);
}
__device__ __forceinline__ float bf2f(unsigned short h) {
    return __uint_as_float(((unsigned)h) << 16);
}

// ---------------- split h (fp32 [n][d]) -> h_hi/h_lo bf16 same layout ----------------
__global__ __launch_bounds__(256) void k_split_h(const float* __restrict__ src,
                                                 unsigned short* __restrict__ dhi,
                                                 unsigned short* __restrict__ dlo) {
    size_t base = ((size_t)blockIdx.x * 256 + threadIdx.x) * 8;
    float4 v0 = *(const float4*)(src + base);
    float4 v1 = *(const float4*)(src + base + 4);
    union { unsigned short s[8]; uint4 v; } hb, lb;
    #pragma unroll
    for (int q = 0; q < 8; q++) {
        float v = q < 4 ? f4c(v0, q) : f4c(v1, q - 4);
        unsigned short hi = f2bf(v);
        hb.s[q] = hi;
        lb.s[q] = f2bf(v - bf2f(hi));
    }
    *(uint4*)(dhi + base) = hb.v;
    *(uint4*)(dlo + base) = lb.v;
}

// ---------------- split W [h][d][f] -> WT_hi/lo [h][f][d] (transposed) ----------------
__global__ __launch_bounds__(256) void k_split_w(const float* __restrict__ W,
                                                 unsigned short* __restrict__ whi,
                                                 unsigned short* __restrict__ wlo) {
    __shared__ float tile[64][65];
    int t = threadIdx.x;
    int h = blockIdx.y;
    int d0 = blockIdx.x * 64;
    #pragma unroll
    for (int kidx = 0; kidx < 4; kidx++) {
        int id = t + 256 * kidx;
        int dd = id >> 4, f4 = (id & 15) * 4;
        float4 v = *(const float4*)(W + ((size_t)(h * DD + d0 + dd)) * FF + f4);
        tile[dd][f4] = v.x; tile[dd][f4 + 1] = v.y; tile[dd][f4 + 2] = v.z; tile[dd][f4 + 3] = v.w;
    }
    __syncthreads();
    int f = t >> 2, c = (t & 3) * 16;
    union { unsigned short s[16]; uint4 v[2]; } hb, lb;
    #pragma unroll
    for (int q = 0; q < 16; q++) {
        float v = tile[c + q][f];
        unsigned short hi = f2bf(v);
        hb.s[q] = hi;
        lb.s[q] = f2bf(v - bf2f(hi));
    }
    uint4* dh = (uint4*)(whi + ((size_t)h * FF + f) * DD + d0 + c);
    uint4* dl = (uint4*)(wlo + ((size_t)h * FF + f) * DD + d0 + c);
    dh[0] = hb.v[0]; dh[1] = hb.v[1];
    dl[0] = lb.v[0]; dl[1] = lb.v[1];
}

// ---------------- hp GEMM on MFMA (3-product hi/lo). Emits hpT_hi/lo + fs/fd. ----------------
__global__ __launch_bounds__(256) void k_hp_mfma(const unsigned short* __restrict__ h_hi,
                                                 const unsigned short* __restrict__ h_lo,
                                                 const unsigned short* __restrict__ whi,
                                                 const unsigned short* __restrict__ wlo,
                                                 const float* __restrict__ a,
                                                 unsigned short* __restrict__ hpT_hi,
                                                 unsigned short* __restrict__ hpT_lo,
                                                 float* __restrict__ fs,
                                                 float* __restrict__ fd) {
    __shared__ char smem[4 * 64 * SP * 2];   // 36864 B
    unsigned short* ah = (unsigned short*)smem;
    unsigned short* al = ah + 64 * SP;
    unsigned short* bh = al + 64 * SP;
    unsigned short* bl = bh + 64 * SP;

    int t = threadIdx.x;
    int h = blockIdx.y;
    int n0 = blockIdx.x * 64;
    int lane = t & 63;
    int w = t >> 6;
    int R0 = (w >> 1) * 32, F0 = (w & 1) * 32;
    int am = lane & 15, aq = lane >> 4;
    int sr = t >> 2, sc = (t & 3) * 16;

    const unsigned short* gah = h_hi + (size_t)(n0 + sr) * DD;
    const unsigned short* gal = h_lo + (size_t)(n0 + sr) * DD;
    const unsigned short* gbh = whi + ((size_t)h * FF + sr) * DD;
    const unsigned short* gbl = wlo + ((size_t)h * FF + sr) * DD;

    f32x4 acc[2][2] = {};
    for (int kk = 0; kk < DD; kk += 64) {
        const uint4* s0 = (const uint4*)(gah + kk + sc);
        const uint4* s1 = (const uint4*)(gal + kk + sc);
        const uint4* s2 = (const uint4*)(gbh + kk + sc);
        const uint4* s3 = (const uint4*)(gbl + kk + sc);
        uint4 v0 = s0[0], v1 = s0[1], u0 = s1[0], u1 = s1[1];
        uint4 w0 = s2[0], w1 = s2[1], x0 = s3[0], x1 = s3[1];
        *(uint4*)(ah + sr * SP + sc) = v0; *(uint4*)(ah + sr * SP + sc + 8) = v1;
        *(uint4*)(al + sr * SP + sc) = u0; *(uint4*)(al + sr * SP + sc + 8) = u1;
        *(uint4*)(bh + sr * SP + sc) = w0; *(uint4*)(bh + sr * SP + sc + 8) = w1;
        *(uint4*)(bl + sr * SP + sc) = x0; *(uint4*)(bl + sr * SP + sc + 8) = x1;
        __syncthreads();
        #pragma unroll
        for (int k2 = 0; k2 < 2; k2++) {
            int ko = k2 * 32 + aq * 8;
            bf16x8 a0h = *(const bf16x8*)(ah + (R0 + am) * SP + ko);
            bf16x8 a1h = *(const bf16x8*)(ah + (R0 + 16 + am) * SP + ko);
            bf16x8 a0l = *(const bf16x8*)(al + (R0 + am) * SP + ko);
            bf16x8 a1l = *(const bf16x8*)(al + (R0 + 16 + am) * SP + ko);
            bf16x8 b0h = *(const bf16x8*)(bh + (F0 + am) * SP + ko);
            bf16x8 b1h = *(const bf16x8*)(bh + (F0 + 16 + am) * SP + ko);
            bf16x8 b0l = *(const bf16x8*)(bl + (F0 + am) * SP + ko);
            bf16x8 b1l = *(const bf16x8*)(bl + (F0 + 16 + am) * SP + ko);
            acc[0][0] = __builtin_amdgcn_mfma_f32_16x16x32_bf16(a0h, b0h, acc[0][0], 0, 0, 0);
            acc[0][1] = __builtin_amdgcn_mfma_f32_16x16x32_bf16(a0h, b1h, acc[0][1], 0, 0, 0);
            acc[1][0] = __builtin_amdgcn_mfma_f32_16x16x32_bf16(a1h, b0h, acc[1][0], 0, 0, 0);
            acc[1][1] = __builtin_amdgcn_mfma_f32_16x16x32_bf16(a1h, b1h, acc[1][1], 0, 0, 0);
            acc[0][0] = __builtin_amdgcn_mfma_f32_16x16x32_bf16(a0h, b0l, acc[0][0], 0, 0, 0);
            acc[0][1] = __builtin_amdgcn_mfma_f32_16x16x32_bf16(a0h, b1l, acc[0][1], 0, 0, 0);
            acc[1][0] = __builtin_amdgcn_mfma_f32_16x16x32_bf16(a1h, b0l, acc[1][0], 0, 0, 0);
            acc[1][1] = __builtin_amdgcn_mfma_f32_16x16x32_bf16(a1h, b1l, acc[1][1], 0, 0, 0);
            acc[0][0] = __builtin_amdgcn_mfma_f32_16x16x32_bf16(a0l, b0h, acc[0][0], 0, 0, 0);
            acc[0][1] = __builtin_amdgcn_mfma_f32_16x16x32_bf16(a0l, b1h, acc[0][1], 0, 0, 0);
            acc[1][0] = __builtin_amdgcn_mfma_f32_16x16x32_bf16(a1l, b0h, acc[1][0], 0, 0, 0);
            acc[1][1] = __builtin_amdgcn_mfma_f32_16x16x32_bf16(a1l, b1h, acc[1][1], 0, 0, 0);
        }
        __syncthreads();
    }

    // Epilogue: pack hi/lo into LDS [f][n] as u32, then coalesced transposed store + fs/fd.
    unsigned* tt = (unsigned*)smem;
    float* rs = (float*)(smem + 17408);
    float* rd = rs + 256;
    float* ash = rd + 256;
    if (t < 128) ash[t] = a[h * 2 * FF + t];
    int col = lane & 15, rbase = (lane >> 4) * 4;
    #pragma unroll
    for (int m16 = 0; m16 < 2; m16++) {
        #pragma unroll
        for (int n16 = 0; n16 < 2; n16++) {
            #pragma unroll
            for (int r = 0; r < 4; r++) {
                int nl = R0 + m16 * 16 + rbase + r;
                int f = F0 + n16 * 16 + col;
                float v = acc[m16][n16][r];
                unsigned short hi = f2bf(v);
                unsigned short lo = f2bf(v - bf2f(hi));
                tt[f * 68 + nl] = (unsigned)hi | ((unsigned)lo << 16);
            }
        }
    }
    __syncthreads();
    {
        int f = t >> 2, c = (t & 3) * 16;
        union { unsigned short s[16]; uint4 v[2]; } hb, lb;
        #pragma unroll
        for (int q = 0; q < 16; q++) {
            unsigned u = tt[f * 68 + c + q];
            hb.s[q] = (unsigned short)(u & 0xffffu);
            lb.s[q] = (unsigned short)(u >> 16);
        }
        uint4* dh = (uint4*)(hpT_hi + ((size_t)h * FF + f) * NN + n0 + c);
        uint4* dl = (uint4*)(hpT_lo + ((size_t)h * FF + f) * NN + n0 + c);
        dh[0] = hb.v[0]; dh[1] = hb.v[1];
        dl[0] = lb.v[0]; dl[1] = lb.v[1];
    }
    {
        int n = t & 63, g = t >> 6;
        float fsp = 0.f, fdp = 0.f;
        #pragma unroll
        for (int q = 0; q < 16; q++) {
            int f = g * 16 + q;
            unsigned u = tt[f * 68 + n];
            float v = bf2f((unsigned short)(u & 0xffffu)) + bf2f((unsigned short)(u >> 16));
            fsp += v * ash[f];
            fdp += v * ash[64 + f];
        }
        rs[g * 64 + n] = fsp;
        rd[g * 64 + n] = fdp;
    }
    __syncthreads();
    if (t < 64) {
        fs[(size_t)h * NN + n0 + t] = rs[t] + rs[64 + t] + rs[128 + t] + rs[192 + t];
        fd[(size_t)h * NN + n0 + t] = rd[t] + rd[64 + t] + rd[128 + t] + rd[192 + t];
    }
}

// ---------------- maxfd ----------------
__global__ __launch_bounds__(256) void k_maxfd(const float* __restrict__ fd,
                                               float* __restrict__ maxfd) {
    __shared__ float red[256];
    int h = blockIdx.x, t = threadIdx.x;
    float m = -1e30f;
    for (int n = t; n < NN; n += 256) m = fmaxf(m, fd[(size_t)h * NN + n]);
    red[t] = m;
    __syncthreads();
    for (int s = 128; s; s >>= 1) {
        if (t < s) red[t] = fmaxf(red[t], red[t + s]);
        __syncthreads();
    }
    if (t == 0) maxfd[h] = red[0];
}

// ---------------- hpsum via colsum of h then dot with W ----------------
__global__ __launch_bounds__(256) void k_colsum(const float* __restrict__ hmat,
                                                float* __restrict__ partial) {
    int b = blockIdx.x, t = threadIdx.x;
    const float* base = hmat + (size_t)b * 64 * DD;
    float s0 = 0.f, s1 = 0.f;
    #pragma unroll 8
    for (int r = 0; r < 64; r++) {
        float2 v = *(const float2*)(base + (size_t)r * DD + t * 2);
        s0 += v.x; s1 += v.y;
    }
    partial[b * DD + t * 2] = s0;
    partial[b * DD + t * 2 + 1] = s1;
}
__global__ __launch_bounds__(256) void k_hpsumW(const float* __restrict__ partial,
                                                const float* __restrict__ W,
                                                float* __restrict__ hpsum) {
    __shared__ float hsum[DD];
    int h = blockIdx.x, t = threadIdx.x;
    for (int d = t; d < DD; d += 256) {
        float s = 0.f;
        #pragma unroll 8
        for (int p = 0; p < 64; p++) s += partial[p * DD + d];
        hsum[d] = s;
    }
    __syncthreads();
    int f = t >> 2, part = t & 3;
    float s = 0.f;
    for (int d = part; d < DD; d += 4) s += hsum[d] * W[((size_t)h * DD + d) * FF + f];
    s += __shfl_xor(s, 1);
    s += __shfl_xor(s, 2);
    if (part == 0) hpsum[h * FF + f] = s;
}

// ---------------- adj bitmask ----------------
__global__ __launch_bounds__(256) void k_adjpack(const int* __restrict__ adj,
                                                 unsigned* __restrict__ adjw) {
    int tid = blockIdx.x * 256 + threadIdx.x;
    int lane = threadIdx.x & 63;
    unsigned long long mask = __ballot(adj[tid] > 0);
    if (lane == 0) {
        int base = tid >> 5;
        adjw[base] = (unsigned)mask;
        adjw[base + 1] = (unsigned)(mask >> 32);
    }
}

// ---------------- attention: weights (VALU) + PV (MFMA), j-split across blockIdx.z ----------
// Stores NON-normalized acc in the FINAL [n][h*F+f] layout so k_combine is a pure
// element-wise gid->gid pass (no cross-thread read/write hazard on d_out).
__global__ __launch_bounds__(256) void k_attn(const float* __restrict__ fs,
                                              const float* __restrict__ fd,
                                              const float* __restrict__ maxfd,
                                              const unsigned* __restrict__ adjw,
                                              const unsigned short* __restrict__ hpT_hi,
                                              const unsigned short* __restrict__ hpT_lo,
                                              float* __restrict__ acc0,
                                              float* __restrict__ acc1,
                                              float* __restrict__ lsumbuf) {
    __shared__ unsigned short pa[64 * SP];
    __shared__ unsigned short hbh[64 * SP];
    __shared__ unsigned short hbl[64 * SP];
    __shared__ float fss[64], ms[64];

    int t = threadIdx.x;
    int h = blockIdx.y;
    int z = blockIdx.z;
    int i0 = blockIdx.x * 64;
    int lane = t & 63;
    int w = t >> 6;

    const float LOG2E = 1.44269504f;
    float mfd = maxfd[h];
    if (t < 64) {
        float fsv = fs[(size_t)h * NN + i0 + t];
        fss[t] = fsv;
        float s = fsv + mfd;
        float m = fmaxf(s, LRELU_ALPHA * s);
        ms[t] = m * LOG2E;
    }
    __syncthreads();

    int wr = t >> 2;
    int wc = (t & 3) * 16;
    int R0 = (w >> 1) * 32, F0 = (w & 1) * 32;
    int am = lane & 15, aq = lane >> 4;
    float part = 0.f;
    f32x4 acc[2][2] = {};

    const unsigned short* gH = hpT_hi + (size_t)h * FF * NN;
    const unsigned short* gL = hpT_lo + (size_t)h * FF * NN;
    const float* fdh = fd + (size_t)h * NN;
    int jb = z * (NN / 2);

    for (int j0 = jb; j0 < jb + NN / 2; j0 += 64) {
        {   // stage hpT hi/lo tiles
            const uint4* sh = (const uint4*)(gH + (size_t)wr * NN + j0 + wc);
            const uint4* sl = (const uint4*)(gL + (size_t)wr * NN + j0 + wc);
            uint4 v0 = sh[0], v1 = sh[1];
            uint4 u0 = sl[0], u1 = sl[1];
            *(uint4*)(hbh + wr * SP + wc) = v0;
            *(uint4*)(hbh + wr * SP + wc + 8) = v1;
            *(uint4*)(hbl + wr * SP + wc) = u0;
            *(uint4*)(hbl + wr * SP + wc + 8) = u1;
        }
        {   // weights
            unsigned word = adjw[(size_t)(i0 + wr) * (NN / 32) + ((j0 + wc) >> 5)];
            unsigned bits = word >> (wc & 31);
            float fsr = fss[wr], mr = ms[wr];
            union { unsigned u[8]; uint4 v[2]; } wb;
            #pragma unroll
            for (int q = 0; q < 4; q++) {
                float4 fdv = *(const float4*)(fdh + j0 + wc + q * 4);
                unsigned eu[4];
                #pragma unroll
                for (int b = 0; b < 4; b++) {
                    float s = fsr + f4c(fdv, b);
                    float l = fmaxf(s, LRELU_ALPHA * s);
                    float e = exp2f(__builtin_fmaf(l, LOG2E, -mr));
                    e = ((bits >> (q * 4 + b)) & 1u) ? e : 0.f;
                    part += e;
                    eu[b] = __float_as_uint(e) + 0x8000u;
                }
                wb.u[q * 2]     = __builtin_amdgcn_perm(eu[1], eu[0], 0x07060302);
                wb.u[q * 2 + 1] = __builtin_amdgcn_perm(eu[3], eu[2], 0x07060302);
            }
            *(uint4*)(pa + wr * SP + wc) = wb.v[0];
            *(uint4*)(pa + wr * SP + wc + 8) = wb.v[1];
        }
        __syncthreads();
        #pragma unroll
        for (int k2 = 0; k2 < 2; k2++) {
            int ko = k2 * 32 + aq * 8;
            bf16x8 a0  = *(const bf16x8*)(pa  + (R0 + am) * SP + ko);
            bf16x8 a1  = *(const bf16x8*)(pa  + (R0 + 16 + am) * SP + ko);
            bf16x8 b0h = *(const bf16x8*)(hbh + (F0 + am) * SP + ko);
            bf16x8 b1h = *(const bf16x8*)(hbh + (F0 + 16 + am) * SP + ko);
            bf16x8 b0l = *(const bf16x8*)(hbl + (F0 + am) * SP + ko);
            bf16x8 b1l = *(const bf16x8*)(hbl + (F0 + 16 + am) * SP + ko);
            acc[0][0] = __builtin_amdgcn_mfma_f32_16x16x32_bf16(a0, b0h, acc[0][0], 0, 0, 0);
            acc[0][1] = __builtin_amdgcn_mfma_f32_16x16x32_bf16(a0, b1h, acc[0][1], 0, 0, 0);
            acc[1][0] = __builtin_amdgcn_mfma_f32_16x16x32_bf16(a1, b0h, acc[1][0], 0, 0, 0);
            acc[1][1] = __builtin_amdgcn_mfma_f32_16x16x32_bf16(a1, b1h, acc[1][1], 0, 0, 0);
            acc[0][0] = __builtin_amdgcn_mfma_f32_16x16x32_bf16(a0, b0l, acc[0][0], 0, 0, 0);
            acc[0][1] = __builtin_amdgcn_mfma_f32_16x16x32_bf16(a0, b1l, acc[0][1], 0, 0, 0);
            acc[1][0] = __builtin_amdgcn_mfma_f32_16x16x32_bf16(a1, b0l, acc[1][0], 0, 0, 0);
            acc[1][1] = __builtin_amdgcn_mfma_f32_16x16x32_bf16(a1, b1l, acc[1][1], 0, 0, 0);
        }
        __syncthreads();
    }

    part += __shfl_xor(part, 1);
    part += __shfl_xor(part, 2);
    if ((t & 3) == 0) lsumbuf[((size_t)z * HH + h) * NN + i0 + wr] = part;

    // store non-normalized acc in [n][h][f] (final) layout
    float* accb = z == 0 ? acc0 : acc1;
    int col = lane & 15, rbase = (lane >> 4) * 4;
    #pragma unroll
    for (int m16 = 0; m16 < 2; m16++) {
        #pragma unroll
        for (int n16 = 0; n16 < 2; n16++) {
            #pragma unroll
            for (int r = 0; r < 4; r++) {
                int row = R0 + m16 * 16 + rbase + r;
                int f = F0 + n16 * 16 + col;
                accb[((size_t)(i0 + row) * HH + h) * FF + f] = acc[m16][n16][r];
            }
        }
    }
}

// ---------------- combine splits, normalize, ELU (pure gid->gid; acc1 aliases outp) --------
__global__ __launch_bounds__(256) void k_combine(const float* __restrict__ acc0,
                                                 const float* acc1,
                                                 const float* __restrict__ lsumbuf,
                                                 const float* __restrict__ hpsum,
                                                 float* outp) {
    int gid = blockIdx.x * 256 + threadIdx.x;    // float4 units over [n][h][f]
    int n = gid >> 7;
    int rem = gid & 127;
    int h = rem >> 4, f4 = (rem & 15) * 4;
    float4 v0 = ((const float4*)acc0)[gid];
    float4 v1 = ((const float4*)acc1)[gid];
    float l = lsumbuf[(size_t)h * NN + n] + lsumbuf[((size_t)HH + h) * NN + n];
    float4 o;
    const float invN = 1.0f / NN;
    #pragma unroll
    for (int c = 0; c < 4; c++) {
        float v;
        if (l > 0.f) v = (f4c(v0, c) + f4c(v1, c)) / l;
        else         v = hpsum[h * FF + f4 + c] * invN;
        f4s(o, c, v > 0.f ? v : __expf(v) - 1.f);
    }
    ((float4*)outp)[gid] = o;
}

extern "C" void kernel_launch(void* const* d_in, const int* in_sizes, int n_in,
                              void* d_out, int out_size, void* d_ws, size_t ws_size,
                              hipStream_t stream) {
    const float* hmat = (const float*)d_in[0];
    const int*   adj  = (const int*)d_in[1];
    const float* W    = (const float*)d_in[2];
    const float* a    = (const float*)d_in[3];
    float* out = (float*)d_out;

    char* ws = (char*)d_ws;
    unsigned short* hpT_hi = (unsigned short*)(ws);                 // 4 MB
    unsigned short* hpT_lo = (unsigned short*)(ws + (4u << 20));    // 4 MB
    unsigned*       adjw   = (unsigned*)(ws + (8u << 20));          // 2 MB
    unsigned short* h_hi   = (unsigned short*)(ws + (10u << 20));   // 4 MB
    unsigned short* h_lo   = (unsigned short*)(ws + (14u << 20));   // 4 MB
    float*          accb0  = (float*)(ws + (10u << 20));            // 8 MB alias (h dead)
    unsigned short* wt_hi  = (unsigned short*)(ws + (18u << 20));   // 512 KB
    unsigned short* wt_lo  = (unsigned short*)(ws + (18u << 20) + (512u << 10));
    float* fs    = (float*)(ws + (19u << 20));                      // 128 KB
    float* fd    = (float*)(ws + (19u << 20) + (128u << 10));       // 128 KB
    float* mxfd  = (float*)(ws + (19u << 20) + (256u << 10));       // 64 B
    float* hpsum = mxfd + 16;                                       // 2 KB
    float* colpart = hpsum + 512;                                   // 128 KB
    float* lsumbuf = colpart + 64 * DD;                             // 256 KB
    float* accb1 = out;                                             // d_out as split-1 scratch

    k_split_h<<<dim3(1024),          256, 0, stream>>>(hmat, h_hi, h_lo);
    k_split_w<<<dim3(DD / 64, HH),   256, 0, stream>>>(W, wt_hi, wt_lo);
    k_hp_mfma<<<dim3(NN / 64, HH),   256, 0, stream>>>(h_hi, h_lo, wt_hi, wt_lo, a,
                                                       hpT_hi, hpT_lo, fs, fd);
    k_maxfd  <<<dim3(HH),            256, 0, stream>>>(fd, mxfd);
    k_colsum <<<dim3(64),            256, 0, stream>>>(hmat, colpart);
    k_hpsumW <<<dim3(HH),            256, 0, stream>>>(colpart, W, hpsum);
    k_adjpack<<<dim3(NN * NN / 256), 256, 0, stream>>>(adj, adjw);
    k_attn   <<<dim3(NN / 64, HH, 2), 256, 0, stream>>>(fs, fd, mxfd, adjw,
                                                        hpT_hi, hpT_lo, accb0, accb1, lsumbuf);
    k_combine<<<dim3(HH * NN * FF / 4 / 256), 256, 0, stream>>>(accb0, accb1, lsumbuf,
                                                                hpsum, out);
}

// Round 6
// 241.944 us; speedup vs baseline: 2.8393x; 1.1210x over previous
//
#include <hip/hip_runtime.h>

#define NN 4096
#define DD 512
#define HH 8
#define FF 64
#define LRELU_ALPHA 0.2f
#define SP 72   // LDS row stride in bf16 elems

typedef __attribute__((ext_vector_type(8))) short bf16x8;
typedef __attribute__((ext_vector_type(4))) float f32x4;

__device__ __forceinline__ float f4c(const float4& v, int k) {
    return k == 0 ? v.x : (k == 1 ? v.y : (k == 2 ? v.z : v.w));
}
__device__ __forceinline__ void f4s(float4& v, int k, float x) {
    if (k == 0) v.x = x; else if (k == 1) v.y = x; else if (k == 2) v.z = x; else v.w = x;
}
__device__ __forceinline__ unsigned short f2bf(float x) {   // RNE float->bf16
    unsigned u = __float_as_uint(x);
    return (unsigned short)((u + 0x7fffu + ((u >> 16) & 1u)) >> 16);
}
__device__ __forceinline__ float bf2f(unsigned short h) {
    return __uint_as_float(((unsigned)h) << 16);
}
// monotone float<->uint key for atomicMax on arbitrary-sign floats
__device__ __forceinline__ unsigned fkey(float x) {
    unsigned u = __float_as_uint(x);
    return (u & 0x80000000u) ? ~u : (u | 0x80000000u);
}
__device__ __forceinline__ float funkey(unsigned k) {
    unsigned u = (k & 0x80000000u) ? (k ^ 0x80000000u) : ~k;
    return __uint_as_float(u);
}

// ================= Kernel 1: fused prep =================
// blocks [0,4096)      : adjpack (16 x 256 ints each, grid-stride)
// blocks [4096,5120)   : split h -> h_hi/h_lo (bf16)
// blocks [5120,5184)   : split+transpose W -> wt_hi/wt_lo [h][f][d]
// blocks [5184,5248)   : column-sum partials of h
__global__ __launch_bounds__(256) void k_prep(const int* __restrict__ adj,
                                              const float* __restrict__ hmat,
                                              const float* __restrict__ W,
                                              unsigned* __restrict__ adjw,
                                              unsigned short* __restrict__ h_hi,
                                              unsigned short* __restrict__ h_lo,
                                              unsigned short* __restrict__ wt_hi,
                                              unsigned short* __restrict__ wt_lo,
                                              float* __restrict__ colpart,
                                              unsigned* __restrict__ mxkey) {
    __shared__ float tile[64][65];
    int b = blockIdx.x, t = threadIdx.x;
    if (b < 4096) {
        int lane = t & 63;
        #pragma unroll
        for (int i = 0; i < 16; i++) {
            int tid = ((b * 16 + i) << 8) + t;
            unsigned long long mask = __ballot(adj[tid] > 0);
            if (lane == 0) {
                int base = tid >> 5;
                adjw[base] = (unsigned)mask;
                adjw[base + 1] = (unsigned)(mask >> 32);
            }
        }
    } else if (b < 5120) {
        if (b == 4096 && t < 8) mxkey[t] = 0u;   // -inf key; consumed after this kernel
        size_t base = ((size_t)(b - 4096) * 256 + t) * 8;
        float4 v0 = *(const float4*)(hmat + base);
        float4 v1 = *(const float4*)(hmat + base + 4);
        union { unsigned short s[8]; uint4 v; } hb, lb;
        #pragma unroll
        for (int q = 0; q < 8; q++) {
            float v = q < 4 ? f4c(v0, q) : f4c(v1, q - 4);
            unsigned short hi = f2bf(v);
            hb.s[q] = hi;
            lb.s[q] = f2bf(v - bf2f(hi));
        }
        *(uint4*)(h_hi + base) = hb.v;
        *(uint4*)(h_lo + base) = lb.v;
    } else if (b < 5184) {
        int idx = b - 5120;
        int h = idx >> 3;
        int d0 = (idx & 7) * 64;
        #pragma unroll
        for (int kidx = 0; kidx < 4; kidx++) {
            int id = t + 256 * kidx;
            int dd = id >> 4, f4i = (id & 15) * 4;
            float4 v = *(const float4*)(W + ((size_t)(h * DD + d0 + dd)) * FF + f4i);
            tile[dd][f4i] = v.x; tile[dd][f4i + 1] = v.y;
            tile[dd][f4i + 2] = v.z; tile[dd][f4i + 3] = v.w;
        }
        __syncthreads();
        int f = t >> 2, c = (t & 3) * 16;
        union { unsigned short s[16]; uint4 v[2]; } hb, lb;
        #pragma unroll
        for (int q = 0; q < 16; q++) {
            float v = tile[c + q][f];
            unsigned short hi = f2bf(v);
            hb.s[q] = hi;
            lb.s[q] = f2bf(v - bf2f(hi));
        }
        uint4* dh = (uint4*)(wt_hi + ((size_t)h * FF + f) * DD + d0 + c);
        uint4* dl = (uint4*)(wt_lo + ((size_t)h * FF + f) * DD + d0 + c);
        dh[0] = hb.v[0]; dh[1] = hb.v[1];
        dl[0] = lb.v[0]; dl[1] = lb.v[1];
    } else {
        int b2 = b - 5184;
        const float* base = hmat + (size_t)b2 * 64 * DD;
        float s0 = 0.f, s1 = 0.f;
        #pragma unroll 8
        for (int r = 0; r < 64; r++) {
            float2 v = *(const float2*)(base + (size_t)r * DD + t * 2);
            s0 += v.x; s1 += v.y;
        }
        colpart[b2 * DD + t * 2] = s0;
        colpart[b2 * DD + t * 2 + 1] = s1;
    }
}

// ================= Kernel 2: hp GEMM (MFMA hi/lo) + fs/fd + maxfd-atomic; col 64 = hpsumW ====
__global__ __launch_bounds__(256) void k_hp_mfma(const unsigned short* __restrict__ h_hi,
                                                 const unsigned short* __restrict__ h_lo,
                                                 const unsigned short* __restrict__ whi,
                                                 const unsigned short* __restrict__ wlo,
                                                 const float* __restrict__ a,
                                                 const float* __restrict__ colpart,
                                                 const float* __restrict__ W,
                                                 unsigned short* __restrict__ hpT_hi,
                                                 unsigned short* __restrict__ hpT_lo,
                                                 float* __restrict__ fs,
                                                 float* __restrict__ fd,
                                                 float* __restrict__ hpsum,
                                                 unsigned* __restrict__ mxkey) {
    __shared__ char smem[4 * 64 * SP * 2];   // 36864 B
    int t = threadIdx.x;
    int h = blockIdx.y;

    if (blockIdx.x == 64) {   // ---- hpsumW branch: hpsum[h][f] = (sum_n h) . W[h] ----
        float* hsum = (float*)smem;
        for (int d = t; d < DD; d += 256) {
            float s = 0.f;
            #pragma unroll 8
            for (int p = 0; p < 64; p++) s += colpart[p * DD + d];
            hsum[d] = s;
        }
        __syncthreads();
        int f = t >> 2, part = t & 3;
        float s = 0.f;
        for (int d = part; d < DD; d += 4) s += hsum[d] * W[((size_t)h * DD + d) * FF + f];
        s += __shfl_xor(s, 1);
        s += __shfl_xor(s, 2);
        if (part == 0) hpsum[h * FF + f] = s;
        return;
    }

    unsigned short* ah = (unsigned short*)smem;
    unsigned short* al = ah + 64 * SP;
    unsigned short* bh = al + 64 * SP;
    unsigned short* bl = bh + 64 * SP;

    int n0 = blockIdx.x * 64;
    int lane = t & 63;
    int w = t >> 6;
    int R0 = (w >> 1) * 32, F0 = (w & 1) * 32;
    int am = lane & 15, aq = lane >> 4;
    int sr = t >> 2, sc = (t & 3) * 16;

    const unsigned short* gah = h_hi + (size_t)(n0 + sr) * DD;
    const unsigned short* gal = h_lo + (size_t)(n0 + sr) * DD;
    const unsigned short* gbh = whi + ((size_t)h * FF + sr) * DD;
    const unsigned short* gbl = wlo + ((size_t)h * FF + sr) * DD;

    f32x4 acc[2][2] = {};
    for (int kk = 0; kk < DD; kk += 64) {
        const uint4* s0 = (const uint4*)(gah + kk + sc);
        const uint4* s1 = (const uint4*)(gal + kk + sc);
        const uint4* s2 = (const uint4*)(gbh + kk + sc);
        const uint4* s3 = (const uint4*)(gbl + kk + sc);
        uint4 v0 = s0[0], v1 = s0[1], u0 = s1[0], u1 = s1[1];
        uint4 w0 = s2[0], w1 = s2[1], x0 = s3[0], x1 = s3[1];
        *(uint4*)(ah + sr * SP + sc) = v0; *(uint4*)(ah + sr * SP + sc + 8) = v1;
        *(uint4*)(al + sr * SP + sc) = u0; *(uint4*)(al + sr * SP + sc + 8) = u1;
        *(uint4*)(bh + sr * SP + sc) = w0; *(uint4*)(bh + sr * SP + sc + 8) = w1;
        *(uint4*)(bl + sr * SP + sc) = x0; *(uint4*)(bl + sr * SP + sc + 8) = x1;
        __syncthreads();
        #pragma unroll
        for (int k2 = 0; k2 < 2; k2++) {
            int ko = k2 * 32 + aq * 8;
            bf16x8 a0h = *(const bf16x8*)(ah + (R0 + am) * SP + ko);
            bf16x8 a1h = *(const bf16x8*)(ah + (R0 + 16 + am) * SP + ko);
            bf16x8 a0l = *(const bf16x8*)(al + (R0 + am) * SP + ko);
            bf16x8 a1l = *(const bf16x8*)(al + (R0 + 16 + am) * SP + ko);
            bf16x8 b0h = *(const bf16x8*)(bh + (F0 + am) * SP + ko);
            bf16x8 b1h = *(const bf16x8*)(bh + (F0 + 16 + am) * SP + ko);
            bf16x8 b0l = *(const bf16x8*)(bl + (F0 + am) * SP + ko);
            bf16x8 b1l = *(const bf16x8*)(bl + (F0 + 16 + am) * SP + ko);
            acc[0][0] = __builtin_amdgcn_mfma_f32_16x16x32_bf16(a0h, b0h, acc[0][0], 0, 0, 0);
            acc[0][1] = __builtin_amdgcn_mfma_f32_16x16x32_bf16(a0h, b1h, acc[0][1], 0, 0, 0);
            acc[1][0] = __builtin_amdgcn_mfma_f32_16x16x32_bf16(a1h, b0h, acc[1][0], 0, 0, 0);
            acc[1][1] = __builtin_amdgcn_mfma_f32_16x16x32_bf16(a1h, b1h, acc[1][1], 0, 0, 0);
            acc[0][0] = __builtin_amdgcn_mfma_f32_16x16x32_bf16(a0h, b0l, acc[0][0], 0, 0, 0);
            acc[0][1] = __builtin_amdgcn_mfma_f32_16x16x32_bf16(a0h, b1l, acc[0][1], 0, 0, 0);
            acc[1][0] = __builtin_amdgcn_mfma_f32_16x16x32_bf16(a1h, b0l, acc[1][0], 0, 0, 0);
            acc[1][1] = __builtin_amdgcn_mfma_f32_16x16x32_bf16(a1h, b1l, acc[1][1], 0, 0, 0);
            acc[0][0] = __builtin_amdgcn_mfma_f32_16x16x32_bf16(a0l, b0h, acc[0][0], 0, 0, 0);
            acc[0][1] = __builtin_amdgcn_mfma_f32_16x16x32_bf16(a0l, b1h, acc[0][1], 0, 0, 0);
            acc[1][0] = __builtin_amdgcn_mfma_f32_16x16x32_bf16(a1l, b0h, acc[1][0], 0, 0, 0);
            acc[1][1] = __builtin_amdgcn_mfma_f32_16x16x32_bf16(a1l, b1h, acc[1][1], 0, 0, 0);
        }
        __syncthreads();
    }

    // Epilogue: pack hi/lo to LDS [f][n], transposed store, fs/fd, maxfd atomic.
    unsigned* tt = (unsigned*)smem;
    float* rs = (float*)(smem + 17408);
    float* rd = rs + 256;
    float* ash = rd + 256;
    if (t < 128) ash[t] = a[h * 2 * FF + t];
    int col = lane & 15, rbase = (lane >> 4) * 4;
    #pragma unroll
    for (int m16 = 0; m16 < 2; m16++) {
        #pragma unroll
        for (int n16 = 0; n16 < 2; n16++) {
            #pragma unroll
            for (int r = 0; r < 4; r++) {
                int nl = R0 + m16 * 16 + rbase + r;
                int f = F0 + n16 * 16 + col;
                float v = acc[m16][n16][r];
                unsigned short hi = f2bf(v);
                unsigned short lo = f2bf(v - bf2f(hi));
                tt[f * 68 + nl] = (unsigned)hi | ((unsigned)lo << 16);
            }
        }
    }
    __syncthreads();
    {
        int f = t >> 2, c = (t & 3) * 16;
        union { unsigned short s[16]; uint4 v[2]; } hb, lb;
        #pragma unroll
        for (int q = 0; q < 16; q++) {
            unsigned u = tt[f * 68 + c + q];
            hb.s[q] = (unsigned short)(u & 0xffffu);
            lb.s[q] = (unsigned short)(u >> 16);
        }
        uint4* dh = (uint4*)(hpT_hi + ((size_t)h * FF + f) * NN + n0 + c);
        uint4* dl = (uint4*)(hpT_lo + ((size_t)h * FF + f) * NN + n0 + c);
        dh[0] = hb.v[0]; dh[1] = hb.v[1];
        dl[0] = lb.v[0]; dl[1] = lb.v[1];
    }
    {
        int n = t & 63, g = t >> 6;
        float fsp = 0.f, fdp = 0.f;
        #pragma unroll
        for (int q = 0; q < 16; q++) {
            int f = g * 16 + q;
            unsigned u = tt[f * 68 + n];
            float v = bf2f((unsigned short)(u & 0xffffu)) + bf2f((unsigned short)(u >> 16));
            fsp += v * ash[f];
            fdp += v * ash[64 + f];
        }
        rs[g * 64 + n] = fsp;
        rd[g * 64 + n] = fdp;
    }
    __syncthreads();
    if (t < 64) {
        float fdv = rd[t] + rd[64 + t] + rd[128 + t] + rd[192 + t];
        fs[(size_t)h * NN + n0 + t] = rs[t] + rs[64 + t] + rs[128 + t] + rs[192 + t];
        fd[(size_t)h * NN + n0 + t] = fdv;
        unsigned key = fkey(fdv);
        #pragma unroll
        for (int off = 32; off; off >>= 1) key = max(key, (unsigned)__shfl_xor((int)key, off));
        if (t == 0) atomicMax(mxkey + h, key);
    }
}

// ================= Kernel 3: attention (weights VALU + PV MFMA), j-split z=2 =================
__global__ __launch_bounds__(256) void k_attn(const float* __restrict__ fs,
                                              const float* __restrict__ fd,
                                              const unsigned* __restrict__ mxkey,
                                              const unsigned* __restrict__ adjw,
                                              const unsigned short* __restrict__ hpT_hi,
                                              const unsigned short* __restrict__ hpT_lo,
                                              float* __restrict__ acc0,
                                              float* __restrict__ acc1,
                                              float* __restrict__ lsumbuf) {
    __shared__ unsigned short pa[64 * SP];
    __shared__ unsigned short hbh[64 * SP];
    __shared__ unsigned short hbl[64 * SP];
    __shared__ float fss[64], ms[64];

    int t = threadIdx.x;
    int h = blockIdx.y;
    int z = blockIdx.z;
    int i0 = blockIdx.x * 64;
    int lane = t & 63;
    int w = t >> 6;

    const float LOG2E = 1.44269504f;
    float mfd = funkey(mxkey[h]);
    if (t < 64) {
        float fsv = fs[(size_t)h * NN + i0 + t];
        fss[t] = fsv;
        float s = fsv + mfd;
        float m = fmaxf(s, LRELU_ALPHA * s);
        ms[t] = m * LOG2E;
    }
    __syncthreads();

    int wr = t >> 2;
    int wc = (t & 3) * 16;
    int R0 = (w >> 1) * 32, F0 = (w & 1) * 32;
    int am = lane & 15, aq = lane >> 4;
    float part = 0.f;
    f32x4 acc[2][2] = {};

    const unsigned short* gH = hpT_hi + (size_t)h * FF * NN;
    const unsigned short* gL = hpT_lo + (size_t)h * FF * NN;
    const float* fdh = fd + (size_t)h * NN;
    int jb = z * (NN / 2);

    for (int j0 = jb; j0 < jb + NN / 2; j0 += 64) {
        {   // stage hpT hi/lo tiles
            const uint4* sh = (const uint4*)(gH + (size_t)wr * NN + j0 + wc);
            const uint4* sl = (const uint4*)(gL + (size_t)wr * NN + j0 + wc);
            uint4 v0 = sh[0], v1 = sh[1];
            uint4 u0 = sl[0], u1 = sl[1];
            *(uint4*)(hbh + wr * SP + wc) = v0;
            *(uint4*)(hbh + wr * SP + wc + 8) = v1;
            *(uint4*)(hbl + wr * SP + wc) = u0;
            *(uint4*)(hbl + wr * SP + wc + 8) = u1;
        }
        {   // weights
            unsigned word = adjw[(size_t)(i0 + wr) * (NN / 32) + ((j0 + wc) >> 5)];
            unsigned bits = word >> (wc & 31);
            float fsr = fss[wr], mr = ms[wr];
            union { unsigned u[8]; uint4 v[2]; } wb;
            #pragma unroll
            for (int q = 0; q < 4; q++) {
                float4 fdv = *(const float4*)(fdh + j0 + wc + q * 4);
                unsigned eu[4];
                #pragma unroll
                for (int b = 0; b < 4; b++) {
                    float s = fsr + f4c(fdv, b);
                    float l = fmaxf(s, LRELU_ALPHA * s);
                    float e = __builtin_amdgcn_exp2f(__builtin_fmaf(l, LOG2E, -mr));
                    e = ((bits >> (q * 4 + b)) & 1u) ? e : 0.f;
                    part += e;
                    eu[b] = __float_as_uint(e) + 0x8000u;
                }
                wb.u[q * 2]     = __builtin_amdgcn_perm(eu[1], eu[0], 0x07060302);
                wb.u[q * 2 + 1] = __builtin_amdgcn_perm(eu[3], eu[2], 0x07060302);
            }
            *(uint4*)(pa + wr * SP + wc) = wb.v[0];
            *(uint4*)(pa + wr * SP + wc + 8) = wb.v[1];
        }
        __syncthreads();
        #pragma unroll
        for (int k2 = 0; k2 < 2; k2++) {
            int ko = k2 * 32 + aq * 8;
            bf16x8 a0  = *(const bf16x8*)(pa  + (R0 + am) * SP + ko);
            bf16x8 a1  = *(const bf16x8*)(pa  + (R0 + 16 + am) * SP + ko);
            bf16x8 b0h = *(const bf16x8*)(hbh + (F0 + am) * SP + ko);
            bf16x8 b1h = *(const bf16x8*)(hbh + (F0 + 16 + am) * SP + ko);
            bf16x8 b0l = *(const bf16x8*)(hbl + (F0 + am) * SP + ko);
            bf16x8 b1l = *(const bf16x8*)(hbl + (F0 + 16 + am) * SP + ko);
            acc[0][0] = __builtin_amdgcn_mfma_f32_16x16x32_bf16(a0, b0h, acc[0][0], 0, 0, 0);
            acc[0][1] = __builtin_amdgcn_mfma_f32_16x16x32_bf16(a0, b1h, acc[0][1], 0, 0, 0);
            acc[1][0] = __builtin_amdgcn_mfma_f32_16x16x32_bf16(a1, b0h, acc[1][0], 0, 0, 0);
            acc[1][1] = __builtin_amdgcn_mfma_f32_16x16x32_bf16(a1, b1h, acc[1][1], 0, 0, 0);
            acc[0][0] = __builtin_amdgcn_mfma_f32_16x16x32_bf16(a0, b0l, acc[0][0], 0, 0, 0);
            acc[0][1] = __builtin_amdgcn_mfma_f32_16x16x32_bf16(a0, b1l, acc[0][1], 0, 0, 0);
            acc[1][0] = __builtin_amdgcn_mfma_f32_16x16x32_bf16(a1, b0l, acc[1][0], 0, 0, 0);
            acc[1][1] = __builtin_amdgcn_mfma_f32_16x16x32_bf16(a1, b1l, acc[1][1], 0, 0, 0);
        }
        __syncthreads();
    }

    part += __shfl_xor(part, 1);
    part += __shfl_xor(part, 2);
    if ((t & 3) == 0) lsumbuf[((size_t)z * HH + h) * NN + i0 + wr] = part;

    float* accb = z == 0 ? acc0 : acc1;
    int col = lane & 15, rbase = (lane >> 4) * 4;
    #pragma unroll
    for (int m16 = 0; m16 < 2; m16++) {
        #pragma unroll
        for (int n16 = 0; n16 < 2; n16++) {
            #pragma unroll
            for (int r = 0; r < 4; r++) {
                int row = R0 + m16 * 16 + rbase + r;
                int f = F0 + n16 * 16 + col;
                accb[((size_t)(i0 + row) * HH + h) * FF + f] = acc[m16][n16][r];
            }
        }
    }
}

// ================= Kernel 4: combine, normalize, ELU (gid->gid; acc1 aliases outp) ==========
__global__ __launch_bounds__(256) void k_combine(const float* __restrict__ acc0,
                                                 const float* acc1,
                                                 const float* __restrict__ lsumbuf,
                                                 const float* __restrict__ hpsum,
                                                 float* outp) {
    int gid = blockIdx.x * 256 + threadIdx.x;    // float4 units over [n][h][f]
    int n = gid >> 7;
    int rem = gid & 127;
    int h = rem >> 4, f4 = (rem & 15) * 4;
    float4 v0 = ((const float4*)acc0)[gid];
    float4 v1 = ((const float4*)acc1)[gid];
    float l = lsumbuf[(size_t)h * NN + n] + lsumbuf[((size_t)HH + h) * NN + n];
    float4 o;
    const float invN = 1.0f / NN;
    #pragma unroll
    for (int c = 0; c < 4; c++) {
        float v;
        if (l > 0.f) v = (f4c(v0, c) + f4c(v1, c)) / l;
        else         v = hpsum[h * FF + f4 + c] * invN;
        f4s(o, c, v > 0.f ? v : __expf(v) - 1.f);
    }
    ((float4*)outp)[gid] = o;
}

extern "C" void kernel_launch(void* const* d_in, const int* in_sizes, int n_in,
                              void* d_out, int out_size, void* d_ws, size_t ws_size,
                              hipStream_t stream) {
    const float* hmat = (const float*)d_in[0];
    const int*   adj  = (const int*)d_in[1];
    const float* W    = (const float*)d_in[2];
    const float* a    = (const float*)d_in[3];
    float* out = (float*)d_out;

    char* ws = (char*)d_ws;
    unsigned short* hpT_hi = (unsigned short*)(ws);                 // 4 MB
    unsigned short* hpT_lo = (unsigned short*)(ws + (4u << 20));    // 4 MB
    unsigned*       adjw   = (unsigned*)(ws + (8u << 20));          // 2 MB
    unsigned short* h_hi   = (unsigned short*)(ws + (10u << 20));   // 4 MB
    unsigned short* h_lo   = (unsigned short*)(ws + (14u << 20));   // 4 MB
    float*          accb0  = (float*)(ws + (10u << 20));            // 8 MB alias (h splits dead)
    unsigned short* wt_hi  = (unsigned short*)(ws + (18u << 20));   // 512 KB
    unsigned short* wt_lo  = (unsigned short*)(ws + (18u << 20) + (512u << 10));
    float* fs    = (float*)(ws + (19u << 20));                      // 128 KB
    float* fd    = (float*)(ws + (19u << 20) + (128u << 10));       // 128 KB
    unsigned* mxkey = (unsigned*)(ws + (19u << 20) + (256u << 10)); // 64 B
    float* hpsum = (float*)(mxkey + 16);                            // 2 KB
    float* colpart = hpsum + 512;                                   // 128 KB
    float* lsumbuf = colpart + 64 * DD;                             // 256 KB
    float* accb1 = out;                                             // d_out as split-1 scratch

    k_prep   <<<dim3(5248),           256, 0, stream>>>(adj, hmat, W, adjw, h_hi, h_lo,
                                                        wt_hi, wt_lo, colpart, mxkey);
    k_hp_mfma<<<dim3(65, 8),          256, 0, stream>>>(h_hi, h_lo, wt_hi, wt_lo, a,
                                                        colpart, W, hpT_hi, hpT_lo,
                                                        fs, fd, hpsum, mxkey);
    k_attn   <<<dim3(NN / 64, HH, 2), 256, 0, stream>>>(fs, fd, mxkey, adjw,
                                                        hpT_hi, hpT_lo, accb0, accb1, lsumbuf);
    k_combine<<<dim3(HH * NN * FF / 4 / 256), 256, 0, stream>>>(accb0, accb1, lsumbuf,
                                                                hpsum, out);
}

// Round 7
// 222.521 us; speedup vs baseline: 3.0872x; 1.0873x over previous
//
#include <hip/hip_runtime.h>

#define NN 4096
#define DD 512
#define HH 8
#define FF 64
#define LRELU_ALPHA 0.2f
#define SP 72   // LDS row stride in bf16 elems

typedef __attribute__((ext_vector_type(8))) short bf16x8;
typedef __attribute__((ext_vector_type(4))) float f32x4;

__device__ __forceinline__ float f4c(const float4& v, int k) {
    return k == 0 ? v.x : (k == 1 ? v.y : (k == 2 ? v.z : v.w));
}
__device__ __forceinline__ void f4s(float4& v, int k, float x) {
    if (k == 0) v.x = x; else if (k == 1) v.y = x; else if (k == 2) v.z = x; else v.w = x;
}
__device__ __forceinline__ unsigned short f2bf(float x) {   // RNE float->bf16
    unsigned u = __float_as_uint(x);
    return (unsigned short)((u + 0x7fffu + ((u >> 16) & 1u)) >> 16);
}
__device__ __forceinline__ float bf2f(unsigned short h) {
    return __uint_as_float(((unsigned)h) << 16);
}
// monotone float<->uint key for atomicMax on arbitrary-sign floats
__device__ __forceinline__ unsigned fkey(float x) {
    unsigned u = __float_as_uint(x);
    return (u & 0x80000000u) ? ~u : (u | 0x80000000u);
}
__device__ __forceinline__ float funkey(unsigned k) {
    unsigned u = (k & 0x80000000u) ? (k ^ 0x80000000u) : ~k;
    return __uint_as_float(u);
}

// ================= Kernel 1: fused prep =================
__global__ __launch_bounds__(256) void k_prep(const int* __restrict__ adj,
                                              const float* __restrict__ hmat,
                                              const float* __restrict__ W,
                                              unsigned* __restrict__ adjw,
                                              unsigned short* __restrict__ h_hi,
                                              unsigned short* __restrict__ h_lo,
                                              unsigned short* __restrict__ wt_hi,
                                              unsigned short* __restrict__ wt_lo,
                                              float* __restrict__ colpart,
                                              unsigned* __restrict__ mxkey) {
    __shared__ float tile[64][65];
    int b = blockIdx.x, t = threadIdx.x;
    if (b < 4096) {
        int lane = t & 63;
        #pragma unroll
        for (int i = 0; i < 16; i++) {
            int tid = ((b * 16 + i) << 8) + t;
            unsigned long long mask = __ballot(adj[tid] > 0);
            if (lane == 0) {
                int base = tid >> 5;
                adjw[base] = (unsigned)mask;
                adjw[base + 1] = (unsigned)(mask >> 32);
            }
        }
    } else if (b < 5120) {
        if (b == 4096 && t < 8) mxkey[t] = 0u;   // -inf key
        size_t base = ((size_t)(b - 4096) * 256 + t) * 8;
        float4 v0 = *(const float4*)(hmat + base);
        float4 v1 = *(const float4*)(hmat + base + 4);
        union { unsigned short s[8]; uint4 v; } hb, lb;
        #pragma unroll
        for (int q = 0; q < 8; q++) {
            float v = q < 4 ? f4c(v0, q) : f4c(v1, q - 4);
            unsigned short hi = f2bf(v);
            hb.s[q] = hi;
            lb.s[q] = f2bf(v - bf2f(hi));
        }
        *(uint4*)(h_hi + base) = hb.v;
        *(uint4*)(h_lo + base) = lb.v;
    } else if (b < 5184) {
        int idx = b - 5120;
        int h = idx >> 3;
        int d0 = (idx & 7) * 64;
        #pragma unroll
        for (int kidx = 0; kidx < 4; kidx++) {
            int id = t + 256 * kidx;
            int dd = id >> 4, f4i = (id & 15) * 4;
            float4 v = *(const float4*)(W + ((size_t)(h * DD + d0 + dd)) * FF + f4i);
            tile[dd][f4i] = v.x; tile[dd][f4i + 1] = v.y;
            tile[dd][f4i + 2] = v.z; tile[dd][f4i + 3] = v.w;
        }
        __syncthreads();
        int f = t >> 2, c = (t & 3) * 16;
        union { unsigned short s[16]; uint4 v[2]; } hb, lb;
        #pragma unroll
        for (int q = 0; q < 16; q++) {
            float v = tile[c + q][f];
            unsigned short hi = f2bf(v);
            hb.s[q] = hi;
            lb.s[q] = f2bf(v - bf2f(hi));
        }
        uint4* dh = (uint4*)(wt_hi + ((size_t)h * FF + f) * DD + d0 + c);
        uint4* dl = (uint4*)(wt_lo + ((size_t)h * FF + f) * DD + d0 + c);
        dh[0] = hb.v[0]; dh[1] = hb.v[1];
        dl[0] = lb.v[0]; dl[1] = lb.v[1];
    } else {
        int b2 = b - 5184;
        const float* base = hmat + (size_t)b2 * 64 * DD;
        float s0 = 0.f, s1 = 0.f;
        #pragma unroll 8
        for (int r = 0; r < 64; r++) {
            float2 v = *(const float2*)(base + (size_t)r * DD + t * 2);
            s0 += v.x; s1 += v.y;
        }
        colpart[b2 * DD + t * 2] = s0;
        colpart[b2 * DD + t * 2 + 1] = s1;
    }
}

// ================= Kernel 2: hp GEMM (MFMA hi/lo) -> hpT_hi + fs/fd + maxfd; col 64 = hpsumW
__global__ __launch_bounds__(256) void k_hp_mfma(const unsigned short* __restrict__ h_hi,
                                                 const unsigned short* __restrict__ h_lo,
                                                 const unsigned short* __restrict__ whi,
                                                 const unsigned short* __restrict__ wlo,
                                                 const float* __restrict__ a,
                                                 const float* __restrict__ colpart,
                                                 const float* __restrict__ W,
                                                 unsigned short* __restrict__ hpT_hi,
                                                 float* __restrict__ fs,
                                                 float* __restrict__ fd,
                                                 float* __restrict__ hpsum,
                                                 unsigned* __restrict__ mxkey) {
    __shared__ char smem[4 * 64 * SP * 2];   // 36864 B
    int t = threadIdx.x;
    int h = blockIdx.y;

    if (blockIdx.x == 64) {   // hpsum[h][f] = (sum_n h) . W[h]
        float* hsum = (float*)smem;
        for (int d = t; d < DD; d += 256) {
            float s = 0.f;
            #pragma unroll 8
            for (int p = 0; p < 64; p++) s += colpart[p * DD + d];
            hsum[d] = s;
        }
        __syncthreads();
        int f = t >> 2, part = t & 3;
        float s = 0.f;
        for (int d = part; d < DD; d += 4) s += hsum[d] * W[((size_t)h * DD + d) * FF + f];
        s += __shfl_xor(s, 1);
        s += __shfl_xor(s, 2);
        if (part == 0) hpsum[h * FF + f] = s;
        return;
    }

    unsigned short* ah = (unsigned short*)smem;
    unsigned short* al = ah + 64 * SP;
    unsigned short* bh = al + 64 * SP;
    unsigned short* bl = bh + 64 * SP;

    int n0 = blockIdx.x * 64;
    int lane = t & 63;
    int w = t >> 6;
    int R0 = (w >> 1) * 32, F0 = (w & 1) * 32;
    int am = lane & 15, aq = lane >> 4;
    int sr = t >> 2, sc = (t & 3) * 16;

    const unsigned short* gah = h_hi + (size_t)(n0 + sr) * DD;
    const unsigned short* gal = h_lo + (size_t)(n0 + sr) * DD;
    const unsigned short* gbh = whi + ((size_t)h * FF + sr) * DD;
    const unsigned short* gbl = wlo + ((size_t)h * FF + sr) * DD;

    f32x4 acc[2][2] = {};
    for (int kk = 0; kk < DD; kk += 64) {
        const uint4* s0 = (const uint4*)(gah + kk + sc);
        const uint4* s1 = (const uint4*)(gal + kk + sc);
        const uint4* s2 = (const uint4*)(gbh + kk + sc);
        const uint4* s3 = (const uint4*)(gbl + kk + sc);
        uint4 v0 = s0[0], v1 = s0[1], u0 = s1[0], u1 = s1[1];
        uint4 w0 = s2[0], w1 = s2[1], x0 = s3[0], x1 = s3[1];
        *(uint4*)(ah + sr * SP + sc) = v0; *(uint4*)(ah + sr * SP + sc + 8) = v1;
        *(uint4*)(al + sr * SP + sc) = u0; *(uint4*)(al + sr * SP + sc + 8) = u1;
        *(uint4*)(bh + sr * SP + sc) = w0; *(uint4*)(bh + sr * SP + sc + 8) = w1;
        *(uint4*)(bl + sr * SP + sc) = x0; *(uint4*)(bl + sr * SP + sc + 8) = x1;
        __syncthreads();
        #pragma unroll
        for (int k2 = 0; k2 < 2; k2++) {
            int ko = k2 * 32 + aq * 8;
            bf16x8 a0h = *(const bf16x8*)(ah + (R0 + am) * SP + ko);
            bf16x8 a1h = *(const bf16x8*)(ah + (R0 + 16 + am) * SP + ko);
            bf16x8 a0l = *(const bf16x8*)(al + (R0 + am) * SP + ko);
            bf16x8 a1l = *(const bf16x8*)(al + (R0 + 16 + am) * SP + ko);
            bf16x8 b0h = *(const bf16x8*)(bh + (F0 + am) * SP + ko);
            bf16x8 b1h = *(const bf16x8*)(bh + (F0 + 16 + am) * SP + ko);
            bf16x8 b0l = *(const bf16x8*)(bl + (F0 + am) * SP + ko);
            bf16x8 b1l = *(const bf16x8*)(bl + (F0 + 16 + am) * SP + ko);
            acc[0][0] = __builtin_amdgcn_mfma_f32_16x16x32_bf16(a0h, b0h, acc[0][0], 0, 0, 0);
            acc[0][1] = __builtin_amdgcn_mfma_f32_16x16x32_bf16(a0h, b1h, acc[0][1], 0, 0, 0);
            acc[1][0] = __builtin_amdgcn_mfma_f32_16x16x32_bf16(a1h, b0h, acc[1][0], 0, 0, 0);
            acc[1][1] = __builtin_amdgcn_mfma_f32_16x16x32_bf16(a1h, b1h, acc[1][1], 0, 0, 0);
            acc[0][0] = __builtin_amdgcn_mfma_f32_16x16x32_bf16(a0h, b0l, acc[0][0], 0, 0, 0);
            acc[0][1] = __builtin_amdgcn_mfma_f32_16x16x32_bf16(a0h, b1l, acc[0][1], 0, 0, 0);
            acc[1][0] = __builtin_amdgcn_mfma_f32_16x16x32_bf16(a1h, b0l, acc[1][0], 0, 0, 0);
            acc[1][1] = __builtin_amdgcn_mfma_f32_16x16x32_bf16(a1h, b1l, acc[1][1], 0, 0, 0);
            acc[0][0] = __builtin_amdgcn_mfma_f32_16x16x32_bf16(a0l, b0h, acc[0][0], 0, 0, 0);
            acc[0][1] = __builtin_amdgcn_mfma_f32_16x16x32_bf16(a0l, b1h, acc[0][1], 0, 0, 0);
            acc[1][0] = __builtin_amdgcn_mfma_f32_16x16x32_bf16(a1l, b0h, acc[1][0], 0, 0, 0);
            acc[1][1] = __builtin_amdgcn_mfma_f32_16x16x32_bf16(a1l, b1h, acc[1][1], 0, 0, 0);
        }
        __syncthreads();
    }

    // Epilogue: pack hi/lo to LDS [f][n] (lo kept for fs/fd accuracy), store hi, fs/fd, maxfd.
    unsigned* tt = (unsigned*)smem;
    float* rs = (float*)(smem + 17408);
    float* rd = rs + 256;
    float* ash = rd + 256;
    if (t < 128) ash[t] = a[h * 2 * FF + t];
    int col = lane & 15, rbase = (lane >> 4) * 4;
    #pragma unroll
    for (int m16 = 0; m16 < 2; m16++) {
        #pragma unroll
        for (int n16 = 0; n16 < 2; n16++) {
            #pragma unroll
            for (int r = 0; r < 4; r++) {
                int nl = R0 + m16 * 16 + rbase + r;
                int f = F0 + n16 * 16 + col;
                float v = acc[m16][n16][r];
                unsigned short hi = f2bf(v);
                unsigned short lo = f2bf(v - bf2f(hi));
                tt[f * 68 + nl] = (unsigned)hi | ((unsigned)lo << 16);
            }
        }
    }
    __syncthreads();
    {
        int f = t >> 2, c = (t & 3) * 16;
        union { unsigned short s[16]; uint4 v[2]; } hb;
        #pragma unroll
        for (int q = 0; q < 16; q++) hb.s[q] = (unsigned short)(tt[f * 68 + c + q] & 0xffffu);
        uint4* dh = (uint4*)(hpT_hi + ((size_t)h * FF + f) * NN + n0 + c);
        dh[0] = hb.v[0]; dh[1] = hb.v[1];
    }
    {
        int n = t & 63, g = t >> 6;
        float fsp = 0.f, fdp = 0.f;
        #pragma unroll
        for (int q = 0; q < 16; q++) {
            int f = g * 16 + q;
            unsigned u = tt[f * 68 + n];
            float v = bf2f((unsigned short)(u & 0xffffu)) + bf2f((unsigned short)(u >> 16));
            fsp += v * ash[f];
            fdp += v * ash[64 + f];
        }
        rs[g * 64 + n] = fsp;
        rd[g * 64 + n] = fdp;
    }
    __syncthreads();
    if (t < 64) {
        float fdv = rd[t] + rd[64 + t] + rd[128 + t] + rd[192 + t];
        fs[(size_t)h * NN + n0 + t] = rs[t] + rs[64 + t] + rs[128 + t] + rs[192 + t];
        fd[(size_t)h * NN + n0 + t] = fdv;
        unsigned key = fkey(fdv);
        #pragma unroll
        for (int off = 32; off; off >>= 1) key = max(key, (unsigned)__shfl_xor((int)key, off));
        if (t == 0) atomicMax(mxkey + h, key);
    }
}

// ================= Kernel 3: attention — weights (VALU) + PV-hi (MFMA) + ones-MFMA l ========
__global__ __launch_bounds__(256) void k_attn(const float* __restrict__ fs,
                                              const float* __restrict__ fd,
                                              const unsigned* __restrict__ mxkey,
                                              const unsigned* __restrict__ adjw,
                                              const unsigned short* __restrict__ hpT_hi,
                                              float* __restrict__ acc0,
                                              float* __restrict__ acc1,
                                              float* __restrict__ lsumbuf) {
    __shared__ unsigned short pa[64 * SP];
    __shared__ unsigned short hbh[64 * SP];
    __shared__ float fss[64], ms[64];

    int t = threadIdx.x;
    int h = blockIdx.y;
    int z = blockIdx.z;
    int i0 = blockIdx.x * 64;
    int lane = t & 63;
    int w = t >> 6;

    const float LOG2E = 1.44269504f;
    float mfd = funkey(mxkey[h]);
    if (t < 64) {
        float fsv = fs[(size_t)h * NN + i0 + t];
        fss[t] = fsv;
        float s = fsv + mfd;
        float m = fmaxf(s, LRELU_ALPHA * s);
        ms[t] = m * LOG2E;
    }
    __syncthreads();

    int wr = t >> 2;
    int wc = (t & 3) * 16;
    int R0 = (w >> 1) * 32, F0 = (w & 1) * 32;
    int am = lane & 15, aq = lane >> 4;
    f32x4 acc[2][2] = {};
    f32x4 accl[2] = {};
    bf16x8 bones;
    #pragma unroll
    for (int i = 0; i < 8; i++) bones[i] = (short)0x3f80;   // bf16 1.0

    const unsigned short* gH = hpT_hi + (size_t)h * FF * NN;
    const float* fdh = fd + (size_t)h * NN;
    int jb = z * (NN / 2);

    for (int j0 = jb; j0 < jb + NN / 2; j0 += 64) {
        {   // stage hp hi tile
            const uint4* sh = (const uint4*)(gH + (size_t)wr * NN + j0 + wc);
            uint4 v0 = sh[0], v1 = sh[1];
            *(uint4*)(hbh + wr * SP + wc) = v0;
            *(uint4*)(hbh + wr * SP + wc + 8) = v1;
        }
        {   // weights (truncated bf16; denominator uses same values via ones-MFMA)
            unsigned word = adjw[(size_t)(i0 + wr) * (NN / 32) + ((j0 + wc) >> 5)];
            unsigned bits = word >> (wc & 31);
            float fsr = fss[wr], mr = ms[wr];
            union { unsigned u[8]; uint4 v[2]; } wb;
            #pragma unroll
            for (int q = 0; q < 4; q++) {
                float4 fdv = *(const float4*)(fdh + j0 + wc + q * 4);
                unsigned eu[4];
                #pragma unroll
                for (int b = 0; b < 4; b++) {
                    float s = fsr + f4c(fdv, b);
                    float l = fmaxf(s, LRELU_ALPHA * s);
                    float e = __builtin_amdgcn_exp2f(__builtin_fmaf(l, LOG2E, -mr));
                    e = ((bits >> (q * 4 + b)) & 1u) ? e : 0.f;
                    eu[b] = __float_as_uint(e);
                }
                wb.u[q * 2]     = __builtin_amdgcn_perm(eu[1], eu[0], 0x07060302);
                wb.u[q * 2 + 1] = __builtin_amdgcn_perm(eu[3], eu[2], 0x07060302);
            }
            *(uint4*)(pa + wr * SP + wc) = wb.v[0];
            *(uint4*)(pa + wr * SP + wc + 8) = wb.v[1];
        }
        __syncthreads();
        #pragma unroll
        for (int k2 = 0; k2 < 2; k2++) {
            int ko = k2 * 32 + aq * 8;
            bf16x8 a0  = *(const bf16x8*)(pa  + (R0 + am) * SP + ko);
            bf16x8 a1  = *(const bf16x8*)(pa  + (R0 + 16 + am) * SP + ko);
            bf16x8 b0h = *(const bf16x8*)(hbh + (F0 + am) * SP + ko);
            bf16x8 b1h = *(const bf16x8*)(hbh + (F0 + 16 + am) * SP + ko);
            acc[0][0] = __builtin_amdgcn_mfma_f32_16x16x32_bf16(a0, b0h, acc[0][0], 0, 0, 0);
            acc[0][1] = __builtin_amdgcn_mfma_f32_16x16x32_bf16(a0, b1h, acc[0][1], 0, 0, 0);
            acc[1][0] = __builtin_amdgcn_mfma_f32_16x16x32_bf16(a1, b0h, acc[1][0], 0, 0, 0);
            acc[1][1] = __builtin_amdgcn_mfma_f32_16x16x32_bf16(a1, b1h, acc[1][1], 0, 0, 0);
            accl[0]   = __builtin_amdgcn_mfma_f32_16x16x32_bf16(a0, bones, accl[0], 0, 0, 0);
            accl[1]   = __builtin_amdgcn_mfma_f32_16x16x32_bf16(a1, bones, accl[1], 0, 0, 0);
        }
        __syncthreads();
    }

    // row-sums: rows R0+m16*16+(lane>>4)*4+r, all cols equal; write from F0==0 waves, col 0
    if ((w & 1) == 0 && (lane & 15) == 0) {
        int rb = (lane >> 4) * 4;
        #pragma unroll
        for (int m16 = 0; m16 < 2; m16++)
            #pragma unroll
            for (int r = 0; r < 4; r++)
                lsumbuf[((size_t)z * HH + h) * NN + i0 + R0 + m16 * 16 + rb + r] = accl[m16][r];
    }

    float* accb = z == 0 ? acc0 : acc1;
    int col = lane & 15, rbase = (lane >> 4) * 4;
    #pragma unroll
    for (int m16 = 0; m16 < 2; m16++) {
        #pragma unroll
        for (int n16 = 0; n16 < 2; n16++) {
            #pragma unroll
            for (int r = 0; r < 4; r++) {
                int row = R0 + m16 * 16 + rbase + r;
                int f = F0 + n16 * 16 + col;
                accb[((size_t)(i0 + row) * HH + h) * FF + f] = acc[m16][n16][r];
            }
        }
    }
}

// ================= Kernel 4: combine, normalize, ELU (gid->gid; acc1 aliases outp) ==========
__global__ __launch_bounds__(256) void k_combine(const float* __restrict__ acc0,
                                                 const float* acc1,
                                                 const float* __restrict__ lsumbuf,
                                                 const float* __restrict__ hpsum,
                                                 float* outp) {
    int gid = blockIdx.x * 256 + threadIdx.x;    // float4 units over [n][h][f]
    int n = gid >> 7;
    int rem = gid & 127;
    int h = rem >> 4, f4 = (rem & 15) * 4;
    float4 v0 = ((const float4*)acc0)[gid];
    float4 v1 = ((const float4*)acc1)[gid];
    float l = lsumbuf[(size_t)h * NN + n] + lsumbuf[((size_t)HH + h) * NN + n];
    float4 o;
    const float invN = 1.0f / NN;
    #pragma unroll
    for (int c = 0; c < 4; c++) {
        float v;
        if (l > 0.f) v = (f4c(v0, c) + f4c(v1, c)) / l;
        else         v = hpsum[h * FF + f4 + c] * invN;
        f4s(o, c, v > 0.f ? v : __expf(v) - 1.f);
    }
    ((float4*)outp)[gid] = o;
}

extern "C" void kernel_launch(void* const* d_in, const int* in_sizes, int n_in,
                              void* d_out, int out_size, void* d_ws, size_t ws_size,
                              hipStream_t stream) {
    const float* hmat = (const float*)d_in[0];
    const int*   adj  = (const int*)d_in[1];
    const float* W    = (const float*)d_in[2];
    const float* a    = (const float*)d_in[3];
    float* out = (float*)d_out;

    char* ws = (char*)d_ws;
    unsigned short* hpT_hi = (unsigned short*)(ws);                 // 4 MB
    unsigned*       adjw   = (unsigned*)(ws + (4u << 20));          // 2 MB
    unsigned short* h_hi   = (unsigned short*)(ws + (6u << 20));    // 4 MB
    unsigned short* h_lo   = (unsigned short*)(ws + (10u << 20));   // 4 MB
    float*          accb0  = (float*)(ws + (6u << 20));             // 8 MB alias (h splits dead)
    unsigned short* wt_hi  = (unsigned short*)(ws + (14u << 20));   // 512 KB
    unsigned short* wt_lo  = (unsigned short*)(ws + (14u << 20) + (512u << 10));
    float* fs    = (float*)(ws + (15u << 20));                      // 128 KB
    float* fd    = (float*)(ws + (15u << 20) + (128u << 10));       // 128 KB
    unsigned* mxkey = (unsigned*)(ws + (15u << 20) + (256u << 10)); // 64 B
    float* hpsum = (float*)(mxkey + 16);                            // 2 KB
    float* colpart = hpsum + 512;                                   // 128 KB
    float* lsumbuf = colpart + 64 * DD;                             // 256 KB
    float* accb1 = out;                                             // d_out as split-1 scratch

    k_prep   <<<dim3(5248),           256, 0, stream>>>(adj, hmat, W, adjw, h_hi, h_lo,
                                                        wt_hi, wt_lo, colpart, mxkey);
    k_hp_mfma<<<dim3(65, 8),          256, 0, stream>>>(h_hi, h_lo, wt_hi, wt_lo, a,
                                                        colpart, W, hpT_hi,
                                                        fs, fd, hpsum, mxkey);
    k_attn   <<<dim3(NN / 64, HH, 2), 256, 0, stream>>>(fs, fd, mxkey, adjw,
                                                        hpT_hi, accb0, accb1, lsumbuf);
    k_combine<<<dim3(HH * NN * FF / 4 / 256), 256, 0, stream>>>(accb0, accb1, lsumbuf,
                                                                hpsum, out);
}

// Round 8
// 212.014 us; speedup vs baseline: 3.2402x; 1.0496x over previous
//
#include <hip/hip_runtime.h>

#define NN 4096
#define DD 512
#define HH 8
#define FF 64
#define LRELU_ALPHA 0.2f
#define SP 72   // LDS row stride in bf16 elems

typedef __attribute__((ext_vector_type(8))) short bf16x8;
typedef __attribute__((ext_vector_type(4))) float f32x4;

__device__ __forceinline__ float f4c(const float4& v, int k) {
    return k == 0 ? v.x : (k == 1 ? v.y : (k == 2 ? v.z : v.w));
}
__device__ __forceinline__ void f4s(float4& v, int k, float x) {
    if (k == 0) v.x = x; else if (k == 1) v.y = x; else if (k == 2) v.z = x; else v.w = x;
}
__device__ __forceinline__ unsigned short f2bf(float x) {   // RNE float->bf16
    unsigned u = __float_as_uint(x);
    return (unsigned short)((u + 0x7fffu + ((u >> 16) & 1u)) >> 16);
}
__device__ __forceinline__ float bf2f(unsigned short h) {
    return __uint_as_float(((unsigned)h) << 16);
}
// monotone float<->uint key for atomicMax on arbitrary-sign floats
__device__ __forceinline__ unsigned fkey(float x) {
    unsigned u = __float_as_uint(x);
    return (u & 0x80000000u) ? ~u : (u | 0x80000000u);
}
__device__ __forceinline__ float funkey(unsigned k) {
    unsigned u = (k & 0x80000000u) ? (k ^ 0x80000000u) : ~k;
    return __uint_as_float(u);
}

// ================= Kernel 1: fused prep =================
// [0,4096)     : adjpack
// [4096,4160)  : split+transpose W -> wt_hi/wt_lo [h][f][d]
// [4160,5184)  : zero accb (8 MB)
// [5184,5200)  : zero lsumbuf (128 KB)
// 5200         : zero mxkey + hpsum
__global__ __launch_bounds__(256) void k_prep(const int* __restrict__ adj,
                                              const float* __restrict__ W,
                                              unsigned* __restrict__ adjw,
                                              unsigned short* __restrict__ wt_hi,
                                              unsigned short* __restrict__ wt_lo,
                                              float* __restrict__ accb,
                                              float* __restrict__ lsumbuf,
                                              unsigned* __restrict__ mxkey,
                                              float* __restrict__ hpsum) {
    __shared__ float tile[64][65];
    int b = blockIdx.x, t = threadIdx.x;
    if (b < 4096) {
        int lane = t & 63;
        #pragma unroll
        for (int i = 0; i < 16; i++) {
            int tid = ((b * 16 + i) << 8) + t;
            unsigned long long mask = __ballot(adj[tid] > 0);
            if (lane == 0) {
                int base = tid >> 5;
                adjw[base] = (unsigned)mask;
                adjw[base + 1] = (unsigned)(mask >> 32);
            }
        }
    } else if (b < 4160) {
        int idx = b - 4096;
        int h = idx >> 3;
        int d0 = (idx & 7) * 64;
        #pragma unroll
        for (int kidx = 0; kidx < 4; kidx++) {
            int id = t + 256 * kidx;
            int dd = id >> 4, f4i = (id & 15) * 4;
            float4 v = *(const float4*)(W + ((size_t)(h * DD + d0 + dd)) * FF + f4i);
            tile[dd][f4i] = v.x; tile[dd][f4i + 1] = v.y;
            tile[dd][f4i + 2] = v.z; tile[dd][f4i + 3] = v.w;
        }
        __syncthreads();
        int f = t >> 2, c = (t & 3) * 16;
        union { unsigned short s[16]; uint4 v[2]; } hb, lb;
        #pragma unroll
        for (int q = 0; q < 16; q++) {
            float v = tile[c + q][f];
            unsigned short hi = f2bf(v);
            hb.s[q] = hi;
            lb.s[q] = f2bf(v - bf2f(hi));
        }
        uint4* dh = (uint4*)(wt_hi + ((size_t)h * FF + f) * DD + d0 + c);
        uint4* dl = (uint4*)(wt_lo + ((size_t)h * FF + f) * DD + d0 + c);
        dh[0] = hb.v[0]; dh[1] = hb.v[1];
        dl[0] = lb.v[0]; dl[1] = lb.v[1];
    } else if (b < 5184) {
        size_t base = (size_t)(b - 4160) * 512 + t * 2;
        float4 z = {0.f, 0.f, 0.f, 0.f};
        ((float4*)accb)[base] = z;
        ((float4*)accb)[base + 1] = z;
    } else if (b < 5200) {
        size_t base = (size_t)(b - 5184) * 512 + t * 2;
        float4 z = {0.f, 0.f, 0.f, 0.f};
        ((float4*)lsumbuf)[base] = z;
        ((float4*)lsumbuf)[base + 1] = z;
    } else {
        if (t < 16) mxkey[t] = 0u;
        hpsum[t] = 0.f;
        hpsum[t + 256] = 0.f;
    }
}

// ================= Kernel 2: hp GEMM (inline fp32->hi/lo split of h; MFMA 3-product) ========
// Emits hpT_hi, fs/fd, maxfd atomic, hpsum column-sum atomic. grid (64, 8).
__global__ __launch_bounds__(256) void k_hp_mfma(const float* __restrict__ hmat,
                                                 const unsigned short* __restrict__ whi,
                                                 const unsigned short* __restrict__ wlo,
                                                 const float* __restrict__ a,
                                                 unsigned short* __restrict__ hpT_hi,
                                                 float* __restrict__ fs,
                                                 float* __restrict__ fd,
                                                 float* __restrict__ hpsum,
                                                 unsigned* __restrict__ mxkey) {
    __shared__ char smem[4 * 64 * SP * 2];   // 36864 B
    unsigned short* ah = (unsigned short*)smem;
    unsigned short* al = ah + 64 * SP;
    unsigned short* bh = al + 64 * SP;
    unsigned short* bl = bh + 64 * SP;

    int t = threadIdx.x;
    int h = blockIdx.y;
    int n0 = blockIdx.x * 64;
    int lane = t & 63;
    int w = t >> 6;
    int R0 = (w >> 1) * 32, F0 = (w & 1) * 32;
    int am = lane & 15, aq = lane >> 4;
    int sr = t >> 2, sc = (t & 3) * 16;

    const float* gha = hmat + (size_t)(n0 + sr) * DD;
    const unsigned short* gbh = whi + ((size_t)h * FF + sr) * DD;
    const unsigned short* gbl = wlo + ((size_t)h * FF + sr) * DD;

    f32x4 acc[2][2] = {};
    for (int kk = 0; kk < DD; kk += 64) {
        // h: fp32 load + inline hi/lo split
        {
            float4 p0 = *(const float4*)(gha + kk + sc);
            float4 p1 = *(const float4*)(gha + kk + sc + 4);
            float4 p2 = *(const float4*)(gha + kk + sc + 8);
            float4 p3 = *(const float4*)(gha + kk + sc + 12);
            union { unsigned short s[16]; uint4 v[2]; } hb, lb;
            #pragma unroll
            for (int q = 0; q < 16; q++) {
                float v = q < 4 ? f4c(p0, q) : q < 8 ? f4c(p1, q - 4)
                          : q < 12 ? f4c(p2, q - 8) : f4c(p3, q - 12);
                unsigned short hi = f2bf(v);
                hb.s[q] = hi;
                lb.s[q] = f2bf(v - bf2f(hi));
            }
            *(uint4*)(ah + sr * SP + sc) = hb.v[0]; *(uint4*)(ah + sr * SP + sc + 8) = hb.v[1];
            *(uint4*)(al + sr * SP + sc) = lb.v[0]; *(uint4*)(al + sr * SP + sc + 8) = lb.v[1];
        }
        {
            const uint4* s2 = (const uint4*)(gbh + kk + sc);
            const uint4* s3 = (const uint4*)(gbl + kk + sc);
            uint4 w0 = s2[0], w1 = s2[1], x0 = s3[0], x1 = s3[1];
            *(uint4*)(bh + sr * SP + sc) = w0; *(uint4*)(bh + sr * SP + sc + 8) = w1;
            *(uint4*)(bl + sr * SP + sc) = x0; *(uint4*)(bl + sr * SP + sc + 8) = x1;
        }
        __syncthreads();
        #pragma unroll
        for (int k2 = 0; k2 < 2; k2++) {
            int ko = k2 * 32 + aq * 8;
            bf16x8 a0h = *(const bf16x8*)(ah + (R0 + am) * SP + ko);
            bf16x8 a1h = *(const bf16x8*)(ah + (R0 + 16 + am) * SP + ko);
            bf16x8 a0l = *(const bf16x8*)(al + (R0 + am) * SP + ko);
            bf16x8 a1l = *(const bf16x8*)(al + (R0 + 16 + am) * SP + ko);
            bf16x8 b0h = *(const bf16x8*)(bh + (F0 + am) * SP + ko);
            bf16x8 b1h = *(const bf16x8*)(bh + (F0 + 16 + am) * SP + ko);
            bf16x8 b0l = *(const bf16x8*)(bl + (F0 + am) * SP + ko);
            bf16x8 b1l = *(const bf16x8*)(bl + (F0 + 16 + am) * SP + ko);
            acc[0][0] = __builtin_amdgcn_mfma_f32_16x16x32_bf16(a0h, b0h, acc[0][0], 0, 0, 0);
            acc[0][1] = __builtin_amdgcn_mfma_f32_16x16x32_bf16(a0h, b1h, acc[0][1], 0, 0, 0);
            acc[1][0] = __builtin_amdgcn_mfma_f32_16x16x32_bf16(a1h, b0h, acc[1][0], 0, 0, 0);
            acc[1][1] = __builtin_amdgcn_mfma_f32_16x16x32_bf16(a1h, b1h, acc[1][1], 0, 0, 0);
            acc[0][0] = __builtin_amdgcn_mfma_f32_16x16x32_bf16(a0h, b0l, acc[0][0], 0, 0, 0);
            acc[0][1] = __builtin_amdgcn_mfma_f32_16x16x32_bf16(a0h, b1l, acc[0][1], 0, 0, 0);
            acc[1][0] = __builtin_amdgcn_mfma_f32_16x16x32_bf16(a1h, b0l, acc[1][0], 0, 0, 0);
            acc[1][1] = __builtin_amdgcn_mfma_f32_16x16x32_bf16(a1h, b1l, acc[1][1], 0, 0, 0);
            acc[0][0] = __builtin_amdgcn_mfma_f32_16x16x32_bf16(a0l, b0h, acc[0][0], 0, 0, 0);
            acc[0][1] = __builtin_amdgcn_mfma_f32_16x16x32_bf16(a0l, b1h, acc[0][1], 0, 0, 0);
            acc[1][0] = __builtin_amdgcn_mfma_f32_16x16x32_bf16(a1l, b0h, acc[1][0], 0, 0, 0);
            acc[1][1] = __builtin_amdgcn_mfma_f32_16x16x32_bf16(a1l, b1h, acc[1][1], 0, 0, 0);
        }
        __syncthreads();
    }

    // Epilogue: pack hi/lo to LDS [f][n], store hi, fs/fd, maxfd atomic, hpsum atomic.
    unsigned* tt = (unsigned*)smem;
    float* rs = (float*)(smem + 17408);
    float* rd = rs + 256;
    float* ash = rd + 256;
    if (t < 128) ash[t] = a[h * 2 * FF + t];
    int col = lane & 15, rbase = (lane >> 4) * 4;
    #pragma unroll
    for (int m16 = 0; m16 < 2; m16++) {
        #pragma unroll
        for (int n16 = 0; n16 < 2; n16++) {
            #pragma unroll
            for (int r = 0; r < 4; r++) {
                int nl = R0 + m16 * 16 + rbase + r;
                int f = F0 + n16 * 16 + col;
                float v = acc[m16][n16][r];
                unsigned short hi = f2bf(v);
                unsigned short lo = f2bf(v - bf2f(hi));
                tt[f * 68 + nl] = (unsigned)hi | ((unsigned)lo << 16);
            }
        }
    }
    __syncthreads();
    {
        int f = t >> 2, c = (t & 3) * 16;
        union { unsigned short s[16]; uint4 v[2]; } hb;
        float csum = 0.f;
        #pragma unroll
        for (int q = 0; q < 16; q++) {
            unsigned u = tt[f * 68 + c + q];
            hb.s[q] = (unsigned short)(u & 0xffffu);
            csum += bf2f((unsigned short)(u & 0xffffu)) + bf2f((unsigned short)(u >> 16));
        }
        uint4* dh = (uint4*)(hpT_hi + ((size_t)h * FF + f) * NN + n0 + c);
        dh[0] = hb.v[0]; dh[1] = hb.v[1];
        csum += __shfl_xor(csum, 1);
        csum += __shfl_xor(csum, 2);
        if ((t & 3) == 0) unsafeAtomicAdd(hpsum + h * FF + f, csum);
    }
    {
        int n = t & 63, g = t >> 6;
        float fsp = 0.f, fdp = 0.f;
        #pragma unroll
        for (int q = 0; q < 16; q++) {
            int f = g * 16 + q;
            unsigned u = tt[f * 68 + n];
            float v = bf2f((unsigned short)(u & 0xffffu)) + bf2f((unsigned short)(u >> 16));
            fsp += v * ash[f];
            fdp += v * ash[64 + f];
        }
        rs[g * 64 + n] = fsp;
        rd[g * 64 + n] = fdp;
    }
    __syncthreads();
    if (t < 64) {
        float fdv = rd[t] + rd[64 + t] + rd[128 + t] + rd[192 + t];
        fs[(size_t)h * NN + n0 + t] = rs[t] + rs[64 + t] + rs[128 + t] + rs[192 + t];
        fd[(size_t)h * NN + n0 + t] = fdv;
        unsigned key = fkey(fdv);
        #pragma unroll
        for (int off = 32; off; off >>= 1) key = max(key, (unsigned)__shfl_xor((int)key, off));
        if (t == 0) atomicMax(mxkey + h, key);
    }
}

// ================= Kernel 3: attention — z-split 4, atomicAdd combine =================
__global__ __launch_bounds__(256) void k_attn(const float* __restrict__ fs,
                                              const float* __restrict__ fd,
                                              const unsigned* __restrict__ mxkey,
                                              const unsigned* __restrict__ adjw,
                                              const unsigned short* __restrict__ hpT_hi,
                                              float* __restrict__ accb,
                                              float* __restrict__ lsumbuf) {
    __shared__ unsigned short pa[64 * SP];
    __shared__ unsigned short hbh[64 * SP];
    __shared__ float fss[64], ms[64];

    int t = threadIdx.x;
    int h = blockIdx.y;
    int z = blockIdx.z;
    int i0 = blockIdx.x * 64;
    int lane = t & 63;
    int w = t >> 6;

    const float LOG2E = 1.44269504f;
    float mfd = funkey(mxkey[h]);
    if (t < 64) {
        float fsv = fs[(size_t)h * NN + i0 + t];
        fss[t] = fsv;
        float s = fsv + mfd;
        float m = fmaxf(s, LRELU_ALPHA * s);
        ms[t] = m * LOG2E;
    }
    __syncthreads();

    int wr = t >> 2;
    int wc = (t & 3) * 16;
    int R0 = (w >> 1) * 32, F0 = (w & 1) * 32;
    int am = lane & 15, aq = lane >> 4;
    f32x4 acc[2][2] = {};
    f32x4 accl[2] = {};
    bf16x8 bones;
    #pragma unroll
    for (int i = 0; i < 8; i++) bones[i] = (short)0x3f80;   // bf16 1.0

    const unsigned short* gH = hpT_hi + (size_t)h * FF * NN;
    const float* fdh = fd + (size_t)h * NN;
    int jb = z * (NN / 4);

    for (int j0 = jb; j0 < jb + NN / 4; j0 += 64) {
        {   // stage hp hi tile
            const uint4* sh = (const uint4*)(gH + (size_t)wr * NN + j0 + wc);
            uint4 v0 = sh[0], v1 = sh[1];
            *(uint4*)(hbh + wr * SP + wc) = v0;
            *(uint4*)(hbh + wr * SP + wc + 8) = v1;
        }
        {   // weights (truncated bf16; denominator via ones-MFMA uses identical values)
            unsigned word = adjw[(size_t)(i0 + wr) * (NN / 32) + ((j0 + wc) >> 5)];
            unsigned bits = word >> (wc & 31);
            float fsr = fss[wr], mr = ms[wr];
            union { unsigned u[8]; uint4 v[2]; } wb;
            #pragma unroll
            for (int q = 0; q < 4; q++) {
                float4 fdv = *(const float4*)(fdh + j0 + wc + q * 4);
                unsigned eu[4];
                #pragma unroll
                for (int b = 0; b < 4; b++) {
                    float s = fsr + f4c(fdv, b);
                    float l = fmaxf(s, LRELU_ALPHA * s);
                    float e = __builtin_amdgcn_exp2f(__builtin_fmaf(l, LOG2E, -mr));
                    e = ((bits >> (q * 4 + b)) & 1u) ? e : 0.f;
                    eu[b] = __float_as_uint(e);
                }
                wb.u[q * 2]     = __builtin_amdgcn_perm(eu[1], eu[0], 0x07060302);
                wb.u[q * 2 + 1] = __builtin_amdgcn_perm(eu[3], eu[2], 0x07060302);
            }
            *(uint4*)(pa + wr * SP + wc) = wb.v[0];
            *(uint4*)(pa + wr * SP + wc + 8) = wb.v[1];
        }
        __syncthreads();
        #pragma unroll
        for (int k2 = 0; k2 < 2; k2++) {
            int ko = k2 * 32 + aq * 8;
            bf16x8 a0  = *(const bf16x8*)(pa  + (R0 + am) * SP + ko);
            bf16x8 a1  = *(const bf16x8*)(pa  + (R0 + 16 + am) * SP + ko);
            bf16x8 b0h = *(const bf16x8*)(hbh + (F0 + am) * SP + ko);
            bf16x8 b1h = *(const bf16x8*)(hbh + (F0 + 16 + am) * SP + ko);
            acc[0][0] = __builtin_amdgcn_mfma_f32_16x16x32_bf16(a0, b0h, acc[0][0], 0, 0, 0);
            acc[0][1] = __builtin_amdgcn_mfma_f32_16x16x32_bf16(a0, b1h, acc[0][1], 0, 0, 0);
            acc[1][0] = __builtin_amdgcn_mfma_f32_16x16x32_bf16(a1, b0h, acc[1][0], 0, 0, 0);
            acc[1][1] = __builtin_amdgcn_mfma_f32_16x16x32_bf16(a1, b1h, acc[1][1], 0, 0, 0);
            accl[0]   = __builtin_amdgcn_mfma_f32_16x16x32_bf16(a0, bones, accl[0], 0, 0, 0);
            accl[1]   = __builtin_amdgcn_mfma_f32_16x16x32_bf16(a1, bones, accl[1], 0, 0, 0);
        }
        __syncthreads();
    }

    // l partials: F0==0 waves (w=0 rows 0-31, w=2 rows 32-63), col 0 lanes
    if ((w & 1) == 0 && (lane & 15) == 0) {
        int rb = (lane >> 4) * 4;
        #pragma unroll
        for (int m16 = 0; m16 < 2; m16++)
            #pragma unroll
            for (int r = 0; r < 4; r++)
                unsafeAtomicAdd(lsumbuf + (size_t)h * NN + i0 + R0 + m16 * 16 + rb + r,
                                accl[m16][r]);
    }

    int col = lane & 15, rbase = (lane >> 4) * 4;
    #pragma unroll
    for (int m16 = 0; m16 < 2; m16++) {
        #pragma unroll
        for (int n16 = 0; n16 < 2; n16++) {
            #pragma unroll
            for (int r = 0; r < 4; r++) {
                int row = R0 + m16 * 16 + rbase + r;
                int f = F0 + n16 * 16 + col;
                unsafeAtomicAdd(accb + ((size_t)(i0 + row) * HH + h) * FF + f,
                                acc[m16][n16][r]);
            }
        }
    }
}

// ================= Kernel 4: normalize, ELU (gid->gid) =================
__global__ __launch_bounds__(256) void k_combine(const float* __restrict__ accb,
                                                 const float* __restrict__ lsumbuf,
                                                 const float* __restrict__ hpsum,
                                                 float* __restrict__ outp) {
    int gid = blockIdx.x * 256 + threadIdx.x;    // float4 units over [n][h][f]
    int n = gid >> 7;
    int rem = gid & 127;
    int h = rem >> 4, f4 = (rem & 15) * 4;
    float4 v0 = ((const float4*)accb)[gid];
    float l = lsumbuf[(size_t)h * NN + n];
    float4 o;
    const float invN = 1.0f / NN;
    #pragma unroll
    for (int c = 0; c < 4; c++) {
        float v;
        if (l > 0.f) v = f4c(v0, c) / l;
        else         v = hpsum[h * FF + f4 + c] * invN;
        f4s(o, c, v > 0.f ? v : __expf(v) - 1.f);
    }
    ((float4*)outp)[gid] = o;
}

extern "C" void kernel_launch(void* const* d_in, const int* in_sizes, int n_in,
                              void* d_out, int out_size, void* d_ws, size_t ws_size,
                              hipStream_t stream) {
    const float* hmat = (const float*)d_in[0];
    const int*   adj  = (const int*)d_in[1];
    const float* W    = (const float*)d_in[2];
    const float* a    = (const float*)d_in[3];
    float* out = (float*)d_out;

    char* ws = (char*)d_ws;
    unsigned short* hpT_hi = (unsigned short*)(ws);                 // 4 MB
    unsigned*       adjw   = (unsigned*)(ws + (4u << 20));          // 2 MB
    float*          accb   = (float*)(ws + (6u << 20));             // 8 MB
    unsigned short* wt_hi  = (unsigned short*)(ws + (14u << 20));   // 512 KB
    unsigned short* wt_lo  = (unsigned short*)(ws + (14u << 20) + (512u << 10));
    float* fs    = (float*)(ws + (15u << 20));                      // 128 KB
    float* fd    = (float*)(ws + (15u << 20) + (128u << 10));       // 128 KB
    unsigned* mxkey = (unsigned*)(ws + (15u << 20) + (256u << 10)); // 64 B
    float* hpsum = (float*)(mxkey + 16);                            // 2 KB
    float* lsumbuf = hpsum + 512;                                   // 128 KB

    k_prep   <<<dim3(5201),           256, 0, stream>>>(adj, W, adjw, wt_hi, wt_lo,
                                                        accb, lsumbuf, mxkey, hpsum);
    k_hp_mfma<<<dim3(64, 8),          256, 0, stream>>>(hmat, wt_hi, wt_lo, a,
                                                        hpT_hi, fs, fd, hpsum, mxkey);
    k_attn   <<<dim3(NN / 64, HH, 4), 256, 0, stream>>>(fs, fd, mxkey, adjw,
                                                        hpT_hi, accb, lsumbuf);
    k_combine<<<dim3(HH * NN * FF / 4 / 256), 256, 0, stream>>>(accb, lsumbuf,
                                                                hpsum, out);
}

// Round 9
// 197.576 us; speedup vs baseline: 3.4769x; 1.0731x over previous
//
#include <hip/hip_runtime.h>

#define NN 4096
#define DD 512
#define HH 8
#define FF 64
#define LRELU_ALPHA 0.2f
#define SP 72   // LDS row stride in bf16 elems

typedef __attribute__((ext_vector_type(8))) short bf16x8;
typedef __attribute__((ext_vector_type(4))) float f32x4;

__device__ __forceinline__ float f4c(const float4& v, int k) {
    return k == 0 ? v.x : (k == 1 ? v.y : (k == 2 ? v.z : v.w));
}
__device__ __forceinline__ void f4s(float4& v, int k, float x) {
    if (k == 0) v.x = x; else if (k == 1) v.y = x; else if (k == 2) v.z = x; else v.w = x;
}
__device__ __forceinline__ unsigned short f2bf(float x) {   // RNE float->bf16
    unsigned u = __float_as_uint(x);
    return (unsigned short)((u + 0x7fffu + ((u >> 16) & 1u)) >> 16);
}
__device__ __forceinline__ float bf2f(unsigned short h) {
    return __uint_as_float(((unsigned)h) << 16);
}
// monotone float<->uint key for atomicMax on arbitrary-sign floats
__device__ __forceinline__ unsigned fkey(float x) {
    unsigned u = __float_as_uint(x);
    return (u & 0x80000000u) ? ~u : (u | 0x80000000u);
}
__device__ __forceinline__ float funkey(unsigned k) {
    unsigned u = (k & 0x80000000u) ? (k ^ 0x80000000u) : ~k;
    return __uint_as_float(u);
}

// ================= Kernel 1: fused prep =================
// [0,4096)     : adjpack
// [4096,4160)  : split+transpose W -> wt_hi/wt_lo [h][f][d]
// 4160         : zero mxkey + hpsum
__global__ __launch_bounds__(256) void k_prep(const int* __restrict__ adj,
                                              const float* __restrict__ W,
                                              unsigned* __restrict__ adjw,
                                              unsigned short* __restrict__ wt_hi,
                                              unsigned short* __restrict__ wt_lo,
                                              unsigned* __restrict__ mxkey,
                                              float* __restrict__ hpsum) {
    __shared__ float tile[64][65];
    int b = blockIdx.x, t = threadIdx.x;
    if (b < 4096) {
        int lane = t & 63;
        #pragma unroll
        for (int i = 0; i < 16; i++) {
            int tid = ((b * 16 + i) << 8) + t;
            unsigned long long mask = __ballot(adj[tid] > 0);
            if (lane == 0) {
                int base = tid >> 5;
                adjw[base] = (unsigned)mask;
                adjw[base + 1] = (unsigned)(mask >> 32);
            }
        }
    } else if (b < 4160) {
        int idx = b - 4096;
        int h = idx >> 3;
        int d0 = (idx & 7) * 64;
        #pragma unroll
        for (int kidx = 0; kidx < 4; kidx++) {
            int id = t + 256 * kidx;
            int dd = id >> 4, f4i = (id & 15) * 4;
            float4 v = *(const float4*)(W + ((size_t)(h * DD + d0 + dd)) * FF + f4i);
            tile[dd][f4i] = v.x; tile[dd][f4i + 1] = v.y;
            tile[dd][f4i + 2] = v.z; tile[dd][f4i + 3] = v.w;
        }
        __syncthreads();
        int f = t >> 2, c = (t & 3) * 16;
        union { unsigned short s[16]; uint4 v[2]; } hb, lb;
        #pragma unroll
        for (int q = 0; q < 16; q++) {
            float v = tile[c + q][f];
            unsigned short hi = f2bf(v);
            hb.s[q] = hi;
            lb.s[q] = f2bf(v - bf2f(hi));
        }
        uint4* dh = (uint4*)(wt_hi + ((size_t)h * FF + f) * DD + d0 + c);
        uint4* dl = (uint4*)(wt_lo + ((size_t)h * FF + f) * DD + d0 + c);
        dh[0] = hb.v[0]; dh[1] = hb.v[1];
        dl[0] = lb.v[0]; dl[1] = lb.v[1];
    } else {
        if (t < 16) mxkey[t] = 0u;
        hpsum[t] = 0.f;
        hpsum[t + 256] = 0.f;
    }
}

// ================= Kernel 2: hp GEMM (inline fp32->hi/lo split of h; MFMA 3-product) ========
// Emits hpT_hi, fs/fd, maxfd atomic, hpsum column-sum atomic. grid (64, 8).
__global__ __launch_bounds__(256) void k_hp_mfma(const float* __restrict__ hmat,
                                                 const unsigned short* __restrict__ whi,
                                                 const unsigned short* __restrict__ wlo,
                                                 const float* __restrict__ a,
                                                 unsigned short* __restrict__ hpT_hi,
                                                 float* __restrict__ fs,
                                                 float* __restrict__ fd,
                                                 float* __restrict__ hpsum,
                                                 unsigned* __restrict__ mxkey) {
    __shared__ char smem[4 * 64 * SP * 2];   // 36864 B
    unsigned short* ah = (unsigned short*)smem;
    unsigned short* al = ah + 64 * SP;
    unsigned short* bh = al + 64 * SP;
    unsigned short* bl = bh + 64 * SP;

    int t = threadIdx.x;
    int h = blockIdx.y;
    int n0 = blockIdx.x * 64;
    int lane = t & 63;
    int w = t >> 6;
    int R0 = (w >> 1) * 32, F0 = (w & 1) * 32;
    int am = lane & 15, aq = lane >> 4;
    int sr = t >> 2, sc = (t & 3) * 16;

    const float* gha = hmat + (size_t)(n0 + sr) * DD;
    const unsigned short* gbh = whi + ((size_t)h * FF + sr) * DD;
    const unsigned short* gbl = wlo + ((size_t)h * FF + sr) * DD;

    f32x4 acc[2][2] = {};
    for (int kk = 0; kk < DD; kk += 64) {
        {   // h: fp32 load + inline hi/lo split
            float4 p0 = *(const float4*)(gha + kk + sc);
            float4 p1 = *(const float4*)(gha + kk + sc + 4);
            float4 p2 = *(const float4*)(gha + kk + sc + 8);
            float4 p3 = *(const float4*)(gha + kk + sc + 12);
            union { unsigned short s[16]; uint4 v[2]; } hb, lb;
            #pragma unroll
            for (int q = 0; q < 16; q++) {
                float v = q < 4 ? f4c(p0, q) : q < 8 ? f4c(p1, q - 4)
                          : q < 12 ? f4c(p2, q - 8) : f4c(p3, q - 12);
                unsigned short hi = f2bf(v);
                hb.s[q] = hi;
                lb.s[q] = f2bf(v - bf2f(hi));
            }
            *(uint4*)(ah + sr * SP + sc) = hb.v[0]; *(uint4*)(ah + sr * SP + sc + 8) = hb.v[1];
            *(uint4*)(al + sr * SP + sc) = lb.v[0]; *(uint4*)(al + sr * SP + sc + 8) = lb.v[1];
        }
        {
            const uint4* s2 = (const uint4*)(gbh + kk + sc);
            const uint4* s3 = (const uint4*)(gbl + kk + sc);
            uint4 w0 = s2[0], w1 = s2[1], x0 = s3[0], x1 = s3[1];
            *(uint4*)(bh + sr * SP + sc) = w0; *(uint4*)(bh + sr * SP + sc + 8) = w1;
            *(uint4*)(bl + sr * SP + sc) = x0; *(uint4*)(bl + sr * SP + sc + 8) = x1;
        }
        __syncthreads();
        #pragma unroll
        for (int k2 = 0; k2 < 2; k2++) {
            int ko = k2 * 32 + aq * 8;
            bf16x8 a0h = *(const bf16x8*)(ah + (R0 + am) * SP + ko);
            bf16x8 a1h = *(const bf16x8*)(ah + (R0 + 16 + am) * SP + ko);
            bf16x8 a0l = *(const bf16x8*)(al + (R0 + am) * SP + ko);
            bf16x8 a1l = *(const bf16x8*)(al + (R0 + 16 + am) * SP + ko);
            bf16x8 b0h = *(const bf16x8*)(bh + (F0 + am) * SP + ko);
            bf16x8 b1h = *(const bf16x8*)(bh + (F0 + 16 + am) * SP + ko);
            bf16x8 b0l = *(const bf16x8*)(bl + (F0 + am) * SP + ko);
            bf16x8 b1l = *(const bf16x8*)(bl + (F0 + 16 + am) * SP + ko);
            acc[0][0] = __builtin_amdgcn_mfma_f32_16x16x32_bf16(a0h, b0h, acc[0][0], 0, 0, 0);
            acc[0][1] = __builtin_amdgcn_mfma_f32_16x16x32_bf16(a0h, b1h, acc[0][1], 0, 0, 0);
            acc[1][0] = __builtin_amdgcn_mfma_f32_16x16x32_bf16(a1h, b0h, acc[1][0], 0, 0, 0);
            acc[1][1] = __builtin_amdgcn_mfma_f32_16x16x32_bf16(a1h, b1h, acc[1][1], 0, 0, 0);
            acc[0][0] = __builtin_amdgcn_mfma_f32_16x16x32_bf16(a0h, b0l, acc[0][0], 0, 0, 0);
            acc[0][1] = __builtin_amdgcn_mfma_f32_16x16x32_bf16(a0h, b1l, acc[0][1], 0, 0, 0);
            acc[1][0] = __builtin_amdgcn_mfma_f32_16x16x32_bf16(a1h, b0l, acc[1][0], 0, 0, 0);
            acc[1][1] = __builtin_amdgcn_mfma_f32_16x16x32_bf16(a1h, b1l, acc[1][1], 0, 0, 0);
            acc[0][0] = __builtin_amdgcn_mfma_f32_16x16x32_bf16(a0l, b0h, acc[0][0], 0, 0, 0);
            acc[0][1] = __builtin_amdgcn_mfma_f32_16x16x32_bf16(a0l, b1h, acc[0][1], 0, 0, 0);
            acc[1][0] = __builtin_amdgcn_mfma_f32_16x16x32_bf16(a1l, b0h, acc[1][0], 0, 0, 0);
            acc[1][1] = __builtin_amdgcn_mfma_f32_16x16x32_bf16(a1l, b1h, acc[1][1], 0, 0, 0);
        }
        __syncthreads();
    }

    // Epilogue: pack hi/lo to LDS [f][n], store hi, fs/fd, maxfd atomic, hpsum atomic.
    unsigned* tt = (unsigned*)smem;
    float* rs = (float*)(smem + 17408);
    float* rd = rs + 256;
    float* ash = rd + 256;
    if (t < 128) ash[t] = a[h * 2 * FF + t];
    int col = lane & 15, rbase = (lane >> 4) * 4;
    #pragma unroll
    for (int m16 = 0; m16 < 2; m16++) {
        #pragma unroll
        for (int n16 = 0; n16 < 2; n16++) {
            #pragma unroll
            for (int r = 0; r < 4; r++) {
                int nl = R0 + m16 * 16 + rbase + r;
                int f = F0 + n16 * 16 + col;
                float v = acc[m16][n16][r];
                unsigned short hi = f2bf(v);
                unsigned short lo = f2bf(v - bf2f(hi));
                tt[f * 68 + nl] = (unsigned)hi | ((unsigned)lo << 16);
            }
        }
    }
    __syncthreads();
    {
        int f = t >> 2, c = (t & 3) * 16;
        union { unsigned short s[16]; uint4 v[2]; } hb;
        float csum = 0.f;
        #pragma unroll
        for (int q = 0; q < 16; q++) {
            unsigned u = tt[f * 68 + c + q];
            hb.s[q] = (unsigned short)(u & 0xffffu);
            csum += bf2f((unsigned short)(u & 0xffffu)) + bf2f((unsigned short)(u >> 16));
        }
        uint4* dh = (uint4*)(hpT_hi + ((size_t)h * FF + f) * NN + n0 + c);
        dh[0] = hb.v[0]; dh[1] = hb.v[1];
        csum += __shfl_xor(csum, 1);
        csum += __shfl_xor(csum, 2);
        if ((t & 3) == 0) unsafeAtomicAdd(hpsum + h * FF + f, csum);
    }
    {
        int n = t & 63, g = t >> 6;
        float fsp = 0.f, fdp = 0.f;
        #pragma unroll
        for (int q = 0; q < 16; q++) {
            int f = g * 16 + q;
            unsigned u = tt[f * 68 + n];
            float v = bf2f((unsigned short)(u & 0xffffu)) + bf2f((unsigned short)(u >> 16));
            fsp += v * ash[f];
            fdp += v * ash[64 + f];
        }
        rs[g * 64 + n] = fsp;
        rd[g * 64 + n] = fdp;
    }
    __syncthreads();
    if (t < 64) {
        float fdv = rd[t] + rd[64 + t] + rd[128 + t] + rd[192 + t];
        fs[(size_t)h * NN + n0 + t] = rs[t] + rs[64 + t] + rs[128 + t] + rs[192 + t];
        fd[(size_t)h * NN + n0 + t] = fdv;
        unsigned key = fkey(fdv);
        #pragma unroll
        for (int off = 32; off; off >>= 1) key = max(key, (unsigned)__shfl_xor((int)key, off));
        if (t == 0) atomicMax(mxkey + h, key);
    }
}

// ================= Kernel 3: attention — 32-row q-tiles, full j sweep, fused epilogue ========
// grid (NN/32, HH). Wave w: rows R0=(w>>1)*16..+16, cols F0=(w&1)*32..+32.
// l (row sum) comes from ones-MFMA in the SAME C/D rows as acc -> normalize in-register.
__global__ __launch_bounds__(256) void k_attn(const float* __restrict__ fs,
                                              const float* __restrict__ fd,
                                              const unsigned* __restrict__ mxkey,
                                              const unsigned* __restrict__ adjw,
                                              const unsigned short* __restrict__ hpT_hi,
                                              const float* __restrict__ hpsum,
                                              float* __restrict__ outp) {
    __shared__ unsigned short pa[32 * SP];
    __shared__ unsigned short hbh[64 * SP];
    __shared__ float fss[32], ms[32];

    int t = threadIdx.x;
    int h = blockIdx.y;
    int i0 = blockIdx.x * 32;
    int lane = t & 63;
    int w = t >> 6;

    const float LOG2E = 1.44269504f;
    float mfd = funkey(mxkey[h]);
    if (t < 32) {
        float fsv = fs[(size_t)h * NN + i0 + t];
        fss[t] = fsv;
        float s = fsv + mfd;
        float m = fmaxf(s, LRELU_ALPHA * s);
        ms[t] = m * LOG2E;
    }
    __syncthreads();

    int wr = t >> 3;            // weight row 0..31
    int wc = (t & 7) * 8;       // 8-j chunk
    int sr = t >> 2, sc = (t & 3) * 16;   // hbh staging
    int R0 = (w >> 1) * 16, F0 = (w & 1) * 32;
    int am = lane & 15, aq = lane >> 4;
    f32x4 acc[2] = {};
    f32x4 accl = {};
    bf16x8 bones;
    #pragma unroll
    for (int i = 0; i < 8; i++) bones[i] = (short)0x3f80;   // bf16 1.0

    const unsigned short* gH = hpT_hi + (size_t)h * FF * NN;
    const float* fdh = fd + (size_t)h * NN;

    for (int j0 = 0; j0 < NN; j0 += 64) {
        {   // stage hp hi tile [f=sr][j=sc..sc+16]
            const uint4* sh = (const uint4*)(gH + (size_t)sr * NN + j0 + sc);
            uint4 v0 = sh[0], v1 = sh[1];
            *(uint4*)(hbh + sr * SP + sc) = v0;
            *(uint4*)(hbh + sr * SP + sc + 8) = v1;
        }
        {   // weights: 8 scores per thread (truncated bf16)
            unsigned word = adjw[(size_t)(i0 + wr) * (NN / 32) + ((j0 + wc) >> 5)];
            unsigned bits = word >> (wc & 31);
            float fsr = fss[wr], mr = ms[wr];
            union { unsigned u[4]; uint4 v; } wb;
            #pragma unroll
            for (int q = 0; q < 2; q++) {
                float4 fdv = *(const float4*)(fdh + j0 + wc + q * 4);
                unsigned eu[4];
                #pragma unroll
                for (int b = 0; b < 4; b++) {
                    float s = fsr + f4c(fdv, b);
                    float l = fmaxf(s, LRELU_ALPHA * s);
                    float e = __builtin_amdgcn_exp2f(__builtin_fmaf(l, LOG2E, -mr));
                    e = ((bits >> (q * 4 + b)) & 1u) ? e : 0.f;
                    eu[b] = __float_as_uint(e);
                }
                wb.u[q * 2]     = __builtin_amdgcn_perm(eu[1], eu[0], 0x07060302);
                wb.u[q * 2 + 1] = __builtin_amdgcn_perm(eu[3], eu[2], 0x07060302);
            }
            *(uint4*)(pa + wr * SP + wc) = wb.v;
        }
        __syncthreads();
        #pragma unroll
        for (int k2 = 0; k2 < 2; k2++) {
            int ko = k2 * 32 + aq * 8;
            bf16x8 a0 = *(const bf16x8*)(pa  + (R0 + am) * SP + ko);
            bf16x8 b0 = *(const bf16x8*)(hbh + (F0 + am) * SP + ko);
            bf16x8 b1 = *(const bf16x8*)(hbh + (F0 + 16 + am) * SP + ko);
            acc[0] = __builtin_amdgcn_mfma_f32_16x16x32_bf16(a0, b0, acc[0], 0, 0, 0);
            acc[1] = __builtin_amdgcn_mfma_f32_16x16x32_bf16(a0, b1, acc[1], 0, 0, 0);
            accl   = __builtin_amdgcn_mfma_f32_16x16x32_bf16(a0, bones, accl, 0, 0, 0);
        }
        __syncthreads();
    }

    // Fused epilogue: l is in accl[r] for the same row as acc[*][r]. Normalize+ELU+store.
    const float invN = 1.0f / NN;
    int col = lane & 15, rbase = (lane >> 4) * 4;
    #pragma unroll
    for (int r = 0; r < 4; r++) {
        int row = i0 + R0 + rbase + r;
        float l = accl[r];
        float rl = 1.f / l;     // l > 0 in non-degenerate case
        #pragma unroll
        for (int n16 = 0; n16 < 2; n16++) {
            int f = F0 + n16 * 16 + col;
            float v;
            if (l > 0.f) v = acc[n16][r] * rl;
            else         v = hpsum[h * FF + f] * invN;   // all-masked row fallback
            v = v > 0.f ? v : __expf(v) - 1.f;
            outp[(size_t)row * (HH * FF) + h * FF + f] = v;
        }
    }
}

extern "C" void kernel_launch(void* const* d_in, const int* in_sizes, int n_in,
                              void* d_out, int out_size, void* d_ws, size_t ws_size,
                              hipStream_t stream) {
    const float* hmat = (const float*)d_in[0];
    const int*   adj  = (const int*)d_in[1];
    const float* W    = (const float*)d_in[2];
    const float* a    = (const float*)d_in[3];
    float* out = (float*)d_out;

    char* ws = (char*)d_ws;
    unsigned short* hpT_hi = (unsigned short*)(ws);                 // 4 MB
    unsigned*       adjw   = (unsigned*)(ws + (4u << 20));          // 2 MB
    unsigned short* wt_hi  = (unsigned short*)(ws + (6u << 20));    // 512 KB
    unsigned short* wt_lo  = (unsigned short*)(ws + (6u << 20) + (512u << 10));
    float* fs    = (float*)(ws + (7u << 20));                       // 128 KB
    float* fd    = (float*)(ws + (7u << 20) + (128u << 10));        // 128 KB
    unsigned* mxkey = (unsigned*)(ws + (7u << 20) + (256u << 10));  // 64 B
    float* hpsum = (float*)(mxkey + 16);                            // 2 KB

    k_prep   <<<dim3(4161),          256, 0, stream>>>(adj, W, adjw, wt_hi, wt_lo,
                                                       mxkey, hpsum);
    k_hp_mfma<<<dim3(64, 8),         256, 0, stream>>>(hmat, wt_hi, wt_lo, a,
                                                       hpT_hi, fs, fd, hpsum, mxkey);
    k_attn   <<<dim3(NN / 32, HH),   256, 0, stream>>>(fs, fd, mxkey, adjw,
                                                       hpT_hi, hpsum, out);
}

// Round 10
// 189.480 us; speedup vs baseline: 3.6255x; 1.0427x over previous
//
#include <hip/hip_runtime.h>

#define NN 4096
#define DD 512
#define HH 8
#define FF 64
#define LRELU_ALPHA 0.2f
#define SP 72   // LDS row stride in bf16 elems

typedef __attribute__((ext_vector_type(8))) short bf16x8;
typedef __attribute__((ext_vector_type(4))) float f32x4;

__device__ __forceinline__ float f4c(const float4& v, int k) {
    return k == 0 ? v.x : (k == 1 ? v.y : (k == 2 ? v.z : v.w));
}
__device__ __forceinline__ void f4s(float4& v, int k, float x) {
    if (k == 0) v.x = x; else if (k == 1) v.y = x; else if (k == 2) v.z = x; else v.w = x;
}
__device__ __forceinline__ unsigned short f2bf(float x) {   // RNE float->bf16
    unsigned u = __float_as_uint(x);
    return (unsigned short)((u + 0x7fffu + ((u >> 16) & 1u)) >> 16);
}
__device__ __forceinline__ float bf2f(unsigned short h) {
    return __uint_as_float(((unsigned)h) << 16);
}
// monotone float<->uint key for atomicMax on arbitrary-sign floats
__device__ __forceinline__ unsigned fkey(float x) {
    unsigned u = __float_as_uint(x);
    return (u & 0x80000000u) ? ~u : (u | 0x80000000u);
}
__device__ __forceinline__ float funkey(unsigned k) {
    unsigned u = (k & 0x80000000u) ? (k ^ 0x80000000u) : ~k;
    return __uint_as_float(u);
}

// ================= Kernel 1: fused prep =================
// [0,4096)     : adjpack
// [4096,4160)  : split+transpose W -> wt_hi/wt_lo [h][f][d]
// 4160         : zero mxkey + hpsum
__global__ __launch_bounds__(256) void k_prep(const int* __restrict__ adj,
                                              const float* __restrict__ W,
                                              unsigned* __restrict__ adjw,
                                              unsigned short* __restrict__ wt_hi,
                                              unsigned short* __restrict__ wt_lo,
                                              unsigned* __restrict__ mxkey,
                                              float* __restrict__ hpsum) {
    __shared__ float tile[64][65];
    int b = blockIdx.x, t = threadIdx.x;
    if (b < 4096) {
        int lane = t & 63;
        #pragma unroll
        for (int i = 0; i < 16; i++) {
            int tid = ((b * 16 + i) << 8) + t;
            unsigned long long mask = __ballot(adj[tid] > 0);
            if (lane == 0) {
                int base = tid >> 5;
                adjw[base] = (unsigned)mask;
                adjw[base + 1] = (unsigned)(mask >> 32);
            }
        }
    } else if (b < 4160) {
        int idx = b - 4096;
        int h = idx >> 3;
        int d0 = (idx & 7) * 64;
        #pragma unroll
        for (int kidx = 0; kidx < 4; kidx++) {
            int id = t + 256 * kidx;
            int dd = id >> 4, f4i = (id & 15) * 4;
            float4 v = *(const float4*)(W + ((size_t)(h * DD + d0 + dd)) * FF + f4i);
            tile[dd][f4i] = v.x; tile[dd][f4i + 1] = v.y;
            tile[dd][f4i + 2] = v.z; tile[dd][f4i + 3] = v.w;
        }
        __syncthreads();
        int f = t >> 2, c = (t & 3) * 16;
        union { unsigned short s[16]; uint4 v[2]; } hb, lb;
        #pragma unroll
        for (int q = 0; q < 16; q++) {
            float v = tile[c + q][f];
            unsigned short hi = f2bf(v);
            hb.s[q] = hi;
            lb.s[q] = f2bf(v - bf2f(hi));
        }
        uint4* dh = (uint4*)(wt_hi + ((size_t)h * FF + f) * DD + d0 + c);
        uint4* dl = (uint4*)(wt_lo + ((size_t)h * FF + f) * DD + d0 + c);
        dh[0] = hb.v[0]; dh[1] = hb.v[1];
        dl[0] = lb.v[0]; dl[1] = lb.v[1];
    } else {
        if (t < 16) mxkey[t] = 0u;
        hpsum[t] = 0.f;
        hpsum[t + 256] = 0.f;
    }
}

// ================= Kernel 2: hp GEMM (inline fp32->hi/lo split of h; MFMA 3-product) ========
// Emits hpT_hi, fs/fd, maxfd atomic, hpsum column-sum atomic. grid (64, 8).
__global__ __launch_bounds__(256) void k_hp_mfma(const float* __restrict__ hmat,
                                                 const unsigned short* __restrict__ whi,
                                                 const unsigned short* __restrict__ wlo,
                                                 const float* __restrict__ a,
                                                 unsigned short* __restrict__ hpT_hi,
                                                 float* __restrict__ fs,
                                                 float* __restrict__ fd,
                                                 float* __restrict__ hpsum,
                                                 unsigned* __restrict__ mxkey) {
    __shared__ char smem[4 * 64 * SP * 2];   // 36864 B
    unsigned short* ah = (unsigned short*)smem;
    unsigned short* al = ah + 64 * SP;
    unsigned short* bh = al + 64 * SP;
    unsigned short* bl = bh + 64 * SP;

    int t = threadIdx.x;
    int h = blockIdx.y;
    int n0 = blockIdx.x * 64;
    int lane = t & 63;
    int w = t >> 6;
    int R0 = (w >> 1) * 32, F0 = (w & 1) * 32;
    int am = lane & 15, aq = lane >> 4;
    int sr = t >> 2, sc = (t & 3) * 16;

    const float* gha = hmat + (size_t)(n0 + sr) * DD;
    const unsigned short* gbh = whi + ((size_t)h * FF + sr) * DD;
    const unsigned short* gbl = wlo + ((size_t)h * FF + sr) * DD;

    f32x4 acc[2][2] = {};
    for (int kk = 0; kk < DD; kk += 64) {
        {   // h: fp32 load + inline hi/lo split
            float4 p0 = *(const float4*)(gha + kk + sc);
            float4 p1 = *(const float4*)(gha + kk + sc + 4);
            float4 p2 = *(const float4*)(gha + kk + sc + 8);
            float4 p3 = *(const float4*)(gha + kk + sc + 12);
            union { unsigned short s[16]; uint4 v[2]; } hb, lb;
            #pragma unroll
            for (int q = 0; q < 16; q++) {
                float v = q < 4 ? f4c(p0, q) : q < 8 ? f4c(p1, q - 4)
                          : q < 12 ? f4c(p2, q - 8) : f4c(p3, q - 12);
                unsigned short hi = f2bf(v);
                hb.s[q] = hi;
                lb.s[q] = f2bf(v - bf2f(hi));
            }
            *(uint4*)(ah + sr * SP + sc) = hb.v[0]; *(uint4*)(ah + sr * SP + sc + 8) = hb.v[1];
            *(uint4*)(al + sr * SP + sc) = lb.v[0]; *(uint4*)(al + sr * SP + sc + 8) = lb.v[1];
        }
        {
            const uint4* s2 = (const uint4*)(gbh + kk + sc);
            const uint4* s3 = (const uint4*)(gbl + kk + sc);
            uint4 w0 = s2[0], w1 = s2[1], x0 = s3[0], x1 = s3[1];
            *(uint4*)(bh + sr * SP + sc) = w0; *(uint4*)(bh + sr * SP + sc + 8) = w1;
            *(uint4*)(bl + sr * SP + sc) = x0; *(uint4*)(bl + sr * SP + sc + 8) = x1;
        }
        __syncthreads();
        #pragma unroll
        for (int k2 = 0; k2 < 2; k2++) {
            int ko = k2 * 32 + aq * 8;
            bf16x8 a0h = *(const bf16x8*)(ah + (R0 + am) * SP + ko);
            bf16x8 a1h = *(const bf16x8*)(ah + (R0 + 16 + am) * SP + ko);
            bf16x8 a0l = *(const bf16x8*)(al + (R0 + am) * SP + ko);
            bf16x8 a1l = *(const bf16x8*)(al + (R0 + 16 + am) * SP + ko);
            bf16x8 b0h = *(const bf16x8*)(bh + (F0 + am) * SP + ko);
            bf16x8 b1h = *(const bf16x8*)(bh + (F0 + 16 + am) * SP + ko);
            bf16x8 b0l = *(const bf16x8*)(bl + (F0 + am) * SP + ko);
            bf16x8 b1l = *(const bf16x8*)(bl + (F0 + 16 + am) * SP + ko);
            acc[0][0] = __builtin_amdgcn_mfma_f32_16x16x32_bf16(a0h, b0h, acc[0][0], 0, 0, 0);
            acc[0][1] = __builtin_amdgcn_mfma_f32_16x16x32_bf16(a0h, b1h, acc[0][1], 0, 0, 0);
            acc[1][0] = __builtin_amdgcn_mfma_f32_16x16x32_bf16(a1h, b0h, acc[1][0], 0, 0, 0);
            acc[1][1] = __builtin_amdgcn_mfma_f32_16x16x32_bf16(a1h, b1h, acc[1][1], 0, 0, 0);
            acc[0][0] = __builtin_amdgcn_mfma_f32_16x16x32_bf16(a0h, b0l, acc[0][0], 0, 0, 0);
            acc[0][1] = __builtin_amdgcn_mfma_f32_16x16x32_bf16(a0h, b1l, acc[0][1], 0, 0, 0);
            acc[1][0] = __builtin_amdgcn_mfma_f32_16x16x32_bf16(a1h, b0l, acc[1][0], 0, 0, 0);
            acc[1][1] = __builtin_amdgcn_mfma_f32_16x16x32_bf16(a1h, b1l, acc[1][1], 0, 0, 0);
            acc[0][0] = __builtin_amdgcn_mfma_f32_16x16x32_bf16(a0l, b0h, acc[0][0], 0, 0, 0);
            acc[0][1] = __builtin_amdgcn_mfma_f32_16x16x32_bf16(a0l, b1h, acc[0][1], 0, 0, 0);
            acc[1][0] = __builtin_amdgcn_mfma_f32_16x16x32_bf16(a1l, b0h, acc[1][0], 0, 0, 0);
            acc[1][1] = __builtin_amdgcn_mfma_f32_16x16x32_bf16(a1l, b1h, acc[1][1], 0, 0, 0);
        }
        __syncthreads();
    }

    // Epilogue: pack hi/lo to LDS [f][n], store hi, fs/fd, maxfd atomic, hpsum atomic.
    unsigned* tt = (unsigned*)smem;
    float* rs = (float*)(smem + 17408);
    float* rd = rs + 256;
    float* ash = rd + 256;
    if (t < 128) ash[t] = a[h * 2 * FF + t];
    int col = lane & 15, rbase = (lane >> 4) * 4;
    #pragma unroll
    for (int m16 = 0; m16 < 2; m16++) {
        #pragma unroll
        for (int n16 = 0; n16 < 2; n16++) {
            #pragma unroll
            for (int r = 0; r < 4; r++) {
                int nl = R0 + m16 * 16 + rbase + r;
                int f = F0 + n16 * 16 + col;
                float v = acc[m16][n16][r];
                unsigned short hi = f2bf(v);
                unsigned short lo = f2bf(v - bf2f(hi));
                tt[f * 68 + nl] = (unsigned)hi | ((unsigned)lo << 16);
            }
        }
    }
    __syncthreads();
    {
        int f = t >> 2, c = (t & 3) * 16;
        union { unsigned short s[16]; uint4 v[2]; } hb;
        float csum = 0.f;
        #pragma unroll
        for (int q = 0; q < 16; q++) {
            unsigned u = tt[f * 68 + c + q];
            hb.s[q] = (unsigned short)(u & 0xffffu);
            csum += bf2f((unsigned short)(u & 0xffffu)) + bf2f((unsigned short)(u >> 16));
        }
        uint4* dh = (uint4*)(hpT_hi + ((size_t)h * FF + f) * NN + n0 + c);
        dh[0] = hb.v[0]; dh[1] = hb.v[1];
        csum += __shfl_xor(csum, 1);
        csum += __shfl_xor(csum, 2);
        if ((t & 3) == 0) unsafeAtomicAdd(hpsum + h * FF + f, csum);
    }
    {
        int n = t & 63, g = t >> 6;
        float fsp = 0.f, fdp = 0.f;
        #pragma unroll
        for (int q = 0; q < 16; q++) {
            int f = g * 16 + q;
            unsigned u = tt[f * 68 + n];
            float v = bf2f((unsigned short)(u & 0xffffu)) + bf2f((unsigned short)(u >> 16));
            fsp += v * ash[f];
            fdp += v * ash[64 + f];
        }
        rs[g * 64 + n] = fsp;
        rd[g * 64 + n] = fdp;
    }
    __syncthreads();
    if (t < 64) {
        float fdv = rd[t] + rd[64 + t] + rd[128 + t] + rd[192 + t];
        fs[(size_t)h * NN + n0 + t] = rs[t] + rs[64 + t] + rs[128 + t] + rs[192 + t];
        fd[(size_t)h * NN + n0 + t] = fdv;
        unsigned key = fkey(fdv);
        #pragma unroll
        for (int off = 32; off; off >>= 1) key = max(key, (unsigned)__shfl_xor((int)key, off));
        if (t == 0) atomicMax(mxkey + h, key);
    }
}

// ================= Kernel 3: attention — 32-row q-tiles, double-buffered j-loop =============
// grid (NN/32, HH). ONE barrier per 64-j iteration: iter k produces tile k+1 into buf^1
// while MFMA consumes tile k from buf. Fused normalize+ELU epilogue (ones-MFMA row sums).
__global__ __launch_bounds__(256) void k_attn(const float* __restrict__ fs,
                                              const float* __restrict__ fd,
                                              const unsigned* __restrict__ mxkey,
                                              const unsigned* __restrict__ adjw,
                                              const unsigned short* __restrict__ hpT_hi,
                                              const float* __restrict__ hpsum,
                                              float* __restrict__ outp) {
    __shared__ unsigned short pa[2][32 * SP];
    __shared__ unsigned short hbh[2][64 * SP];
    __shared__ float fss[32], ms[32];

    int t = threadIdx.x;
    int h = blockIdx.y;
    int i0 = blockIdx.x * 32;
    int lane = t & 63;
    int w = t >> 6;

    const float LOG2E = 1.44269504f;
    float mfd = funkey(mxkey[h]);
    if (t < 32) {
        float fsv = fs[(size_t)h * NN + i0 + t];
        fss[t] = fsv;
        float s = fsv + mfd;
        float m = fmaxf(s, LRELU_ALPHA * s);
        ms[t] = m * LOG2E;
    }
    __syncthreads();

    int wr = t >> 3;            // weight row 0..31
    int wc = (t & 7) * 8;       // 8-j chunk
    int sr = t >> 2, sc = (t & 3) * 16;   // hbh staging
    int R0 = (w >> 1) * 16, F0 = (w & 1) * 32;
    int am = lane & 15, aq = lane >> 4;
    f32x4 acc[2] = {};
    f32x4 accl = {};
    bf16x8 bones;
    #pragma unroll
    for (int i = 0; i < 8; i++) bones[i] = (short)0x3f80;   // bf16 1.0

    const unsigned short* gH = hpT_hi + (size_t)h * FF * NN;
    const float* fdh = fd + (size_t)h * NN;
    float fsr = fss[wr], mr = ms[wr];

    auto produce = [&](int j0, int buf) {
        {   // stage hp hi tile [f=sr][j=sc..sc+16]
            const uint4* sh = (const uint4*)(gH + (size_t)sr * NN + j0 + sc);
            uint4 v0 = sh[0], v1 = sh[1];
            *(uint4*)(&hbh[buf][sr * SP + sc]) = v0;
            *(uint4*)(&hbh[buf][sr * SP + sc + 8]) = v1;
        }
        {   // weights: 8 scores per thread (truncated bf16)
            unsigned word = adjw[(size_t)(i0 + wr) * (NN / 32) + ((j0 + wc) >> 5)];
            unsigned bits = word >> (wc & 31);
            union { unsigned u[4]; uint4 v; } wb;
            #pragma unroll
            for (int q = 0; q < 2; q++) {
                float4 fdv = *(const float4*)(fdh + j0 + wc + q * 4);
                unsigned eu[4];
                #pragma unroll
                for (int b = 0; b < 4; b++) {
                    float s = fsr + f4c(fdv, b);
                    float l = fmaxf(s, LRELU_ALPHA * s);
                    float e = __builtin_amdgcn_exp2f(__builtin_fmaf(l, LOG2E, -mr));
                    e = ((bits >> (q * 4 + b)) & 1u) ? e : 0.f;
                    eu[b] = __float_as_uint(e);
                }
                wb.u[q * 2]     = __builtin_amdgcn_perm(eu[1], eu[0], 0x07060302);
                wb.u[q * 2 + 1] = __builtin_amdgcn_perm(eu[3], eu[2], 0x07060302);
            }
            *(uint4*)(&pa[buf][wr * SP + wc]) = wb.v;
        }
    };

    produce(0, 0);
    __syncthreads();
    for (int j0 = 0; j0 < NN; j0 += 64) {
        int cur = (j0 >> 6) & 1;
        if (j0 + 64 < NN) produce(j0 + 64, cur ^ 1);
        #pragma unroll
        for (int k2 = 0; k2 < 2; k2++) {
            int ko = k2 * 32 + aq * 8;
            bf16x8 a0 = *(const bf16x8*)(&pa[cur][(R0 + am) * SP + ko]);
            bf16x8 b0 = *(const bf16x8*)(&hbh[cur][(F0 + am) * SP + ko]);
            bf16x8 b1 = *(const bf16x8*)(&hbh[cur][(F0 + 16 + am) * SP + ko]);
            acc[0] = __builtin_amdgcn_mfma_f32_16x16x32_bf16(a0, b0, acc[0], 0, 0, 0);
            acc[1] = __builtin_amdgcn_mfma_f32_16x16x32_bf16(a0, b1, acc[1], 0, 0, 0);
            accl   = __builtin_amdgcn_mfma_f32_16x16x32_bf16(a0, bones, accl, 0, 0, 0);
        }
        __syncthreads();
    }

    // Fused epilogue: l is in accl[r] for the same row as acc[*][r]. Normalize+ELU+store.
    const float invN = 1.0f / NN;
    int col = lane & 15, rbase = (lane >> 4) * 4;
    #pragma unroll
    for (int r = 0; r < 4; r++) {
        int row = i0 + R0 + rbase + r;
        float l = accl[r];
        float rl = 1.f / l;     // l > 0 in non-degenerate case
        #pragma unroll
        for (int n16 = 0; n16 < 2; n16++) {
            int f = F0 + n16 * 16 + col;
            float v;
            if (l > 0.f) v = acc[n16][r] * rl;
            else         v = hpsum[h * FF + f] * invN;   // all-masked row fallback
            v = v > 0.f ? v : __expf(v) - 1.f;
            outp[(size_t)row * (HH * FF) + h * FF + f] = v;
        }
    }
}

extern "C" void kernel_launch(void* const* d_in, const int* in_sizes, int n_in,
                              void* d_out, int out_size, void* d_ws, size_t ws_size,
                              hipStream_t stream) {
    const float* hmat = (const float*)d_in[0];
    const int*   adj  = (const int*)d_in[1];
    const float* W    = (const float*)d_in[2];
    const float* a    = (const float*)d_in[3];
    float* out = (float*)d_out;

    char* ws = (char*)d_ws;
    unsigned short* hpT_hi = (unsigned short*)(ws);                 // 4 MB
    unsigned*       adjw   = (unsigned*)(ws + (4u << 20));          // 2 MB
    unsigned short* wt_hi  = (unsigned short*)(ws + (6u << 20));    // 512 KB
    unsigned short* wt_lo  = (unsigned short*)(ws + (6u << 20) + (512u << 10));
    float* fs    = (float*)(ws + (7u << 20));                       // 128 KB
    float* fd    = (float*)(ws + (7u << 20) + (128u << 10));        // 128 KB
    unsigned* mxkey = (unsigned*)(ws + (7u << 20) + (256u << 10));  // 64 B
    float* hpsum = (float*)(mxkey + 16);                            // 2 KB

    k_prep   <<<dim3(4161),          256, 0, stream>>>(adj, W, adjw, wt_hi, wt_lo,
                                                       mxkey, hpsum);
    k_hp_mfma<<<dim3(64, 8),         256, 0, stream>>>(hmat, wt_hi, wt_lo, a,
                                                       hpT_hi, fs, fd, hpsum, mxkey);
    k_attn   <<<dim3(NN / 32, HH),   256, 0, stream>>>(fs, fd, mxkey, adjw,
                                                       hpT_hi, hpsum, out);
}